// Round 13
// baseline (258.479 us; speedup 1.0000x reference)
//
#include <hip/hip_runtime.h>

// ConvCrossAttention on MI355X (gfx950), bf16 MFMA implementation.
// R13: convs switched to BK=32 (32/16/24 KB LDS -> 4+ blocks/CU, 2x TLP to
//      overlap barrier drains; LDS-BW per FLOP unchanged). 64B-row swizzle
//      g=hi4^((row>>1)&3) on both stage-source and reads (2-way, free).
//      attn/prep unchanged from R12.

typedef __attribute__((ext_vector_type(8))) short short8;
typedef __attribute__((ext_vector_type(4))) float f32x4;
typedef unsigned short us;

__device__ __forceinline__ float bf2f(us u) {
  union { unsigned int i; float f; } v; v.i = ((unsigned int)u) << 16; return v.f;
}
__device__ __forceinline__ us f2bf(float f) {
  union { float f; unsigned int i; } v; v.f = f;
  unsigned int x = v.i;
  return (us)((x + 0x7fffu + ((x >> 16) & 1u)) >> 16);
}

typedef __attribute__((address_space(3))) unsigned int as3_uint;
typedef const __attribute__((address_space(1))) unsigned int as1_uint;
__device__ __forceinline__ void gload16(const us* g, us* l) {
  __builtin_amdgcn_global_load_lds((as1_uint*)g, (as3_uint*)l, 16, 0, 0);
}
__device__ __forceinline__ unsigned int cvt_pk_bf16(float a, float b) {
  unsigned int r;
  asm("v_cvt_pk_bf16_f32 %0, %1, %2" : "=v"(r) : "v"(a), "v"(b));
  return r;
}
__device__ __forceinline__ float fast_exp2(float x) {
  float r;
  asm("v_exp_f32 %0, %1" : "=v"(r) : "v"(x));
  return r;
}
// sin/cos via HW transcendentals (input: revolutions, fract-reduced).
__device__ __forceinline__ void fsincos(float ang, float* sn, float* cs) {
  float r = ang * 0.15915494309f;
  r = r - floorf(r);
  float s, c;
  asm("v_sin_f32 %0, %1" : "=v"(s) : "v"(r));
  asm("v_cos_f32 %0, %1" : "=v"(c) : "v"(r));
  *sn = s; *cs = c;
}

// ================================================= fused prep kernel (unchanged)
__device__ __forceinline__ void transpose_body(
    const float* __restrict__ in, us* __restrict__ outT,
    int b, int y, int ci0, int H, int W, int logW) {
  const int C = 512;
  int padW = W + 2, Ppad = (H + 2) * padW;
  __shared__ float tile[64][65];
  int nt = W * 64;
  for (int idx = threadIdx.x; idx < nt; idx += 256) {
    int ci = idx >> logW, x = idx & (W - 1);
    tile[ci][x] = in[(((size_t)b * C + ci0 + ci) * H + y) * W + x];
  }
  __syncthreads();
  int nt2 = W * 32;
  for (int idx = threadIdx.x; idx < nt2; idx += 256) {
    int px = idx >> 5, c2 = idx & 31;
    unsigned int val = (unsigned int)f2bf(tile[c2 * 2][px]) |
                       ((unsigned int)f2bf(tile[c2 * 2 + 1][px]) << 16);
    *(unsigned int*)(outT + ((size_t)b * Ppad + (size_t)(y + 1) * padW + (px + 1)) * C +
                     ci0 + c2 * 2) = val;
  }
}

__global__ __launch_bounds__(256) void prep_all(
    const float* __restrict__ x, const float* __restrict__ cross,
    const float* __restrict__ wq, const float* __restrict__ wk,
    const float* __restrict__ wv, const float* __restrict__ wo,
    const float* __restrict__ lq1, const float* __restrict__ lq2,
    const float* __restrict__ lk1, const float* __restrict__ lk2,
    us* __restrict__ xpadT, us* __restrict__ cpadT, us* __restrict__ apad,
    us* __restrict__ oq, us* __restrict__ ok, us* __restrict__ ov,
    us* __restrict__ oo, float* __restrict__ lam) {
  int bid = blockIdx.x, tid = threadIdx.x;
  if (bid < 326) {
    int g = bid * 4 + (tid >> 6);
    int t = tid & 63;
    us* base; int W, b, i;
    if (g < 520)      { base = xpadT; W = 64; b = g >= 260; i = g - b * 260; }
    else if (g < 784) { base = cpadT; W = 32; int gg = g - 520; b = gg >= 132; i = gg - b * 132; }
    else              { base = apad; W = 64; int gg = g - 784; b = gg >= 260; i = gg - b * 260; }
    int padW = W + 2, nb = 2 * padW;
    int yy, xx;
    if (i < padW)    { yy = 0; xx = i; }
    else if (i < nb) { yy = W + 1; xx = i - padW; }
    else             { int j = i - nb; yy = 1 + (j >> 1); xx = (j & 1) * (W + 1); }
    size_t p = ((size_t)b * padW * padW + (size_t)yy * padW + xx) * 512 + t * 8;
    *(int4*)(base + p) = make_int4(0, 0, 0, 0);
  } else if (bid < 1350) {
    int i = bid - 326;
    transpose_body(x, xpadT, i >> 9, (i >> 3) & 63, (i & 7) * 64, 64, 64, 6);
  } else if (bid < 1862) {
    int i = bid - 1350;
    transpose_body(cross, cpadT, i >> 8, (i >> 3) & 31, (i & 7) * 64, 32, 32, 5);
  } else if (bid < 4166) {
    int blk = bid - 1862;
    const float* src; us* dst; int Cout, co;
    if (blk < 1024)      { src = wq; dst = oq; Cout = 1024; co = blk; }
    else if (blk < 1536) { src = wk; dst = ok; Cout = 512;  co = blk - 1024; }
    else if (blk < 1792) { src = wv; dst = ov; Cout = 256;  co = blk - 1536; }
    else                 { src = wo; dst = oo; Cout = 512;  co = blk - 1792; }
    __shared__ us l[4608];
    const float* s0 = src + (size_t)co * 4608;
#pragma unroll
    for (int k = 0; k < 18; ++k) { int i = k * 256 + tid; l[i] = f2bf(s0[i]); }
    __syncthreads();
#pragma unroll
    for (int k = 0; k < 9; ++k) {
      int j = k * 256 + tid;
      int t = j >> 8, c2 = j & 255;
      unsigned int val = (unsigned int)l[(c2 * 2) * 9 + t] |
                         ((unsigned int)l[(c2 * 2 + 1) * 9 + t] << 16);
      *(unsigned int*)(dst + (size_t)t * Cout * 512 + (size_t)co * 512 + c2 * 2) = val;
    }
  } else {
    int h = tid >> 5, d = tid & 31;
    float s1 = lq1[h * 64 + d] * lk1[h * 64 + d] +
               lq1[h * 64 + d + 32] * lk1[h * 64 + d + 32];
    float s2 = lq2[h * 64 + d] * lk2[h * 64 + d] +
               lq2[h * 64 + d + 32] * lk2[h * 64 + d + 32];
    for (int m = 16; m; m >>= 1) {
      s1 += __shfl_xor(s1, m);
      s2 += __shfl_xor(s2, m);
    }
    if (d == 0) lam[h] = -(expf(s1) - expf(s2) + 0.2f);
  }
}

// ================================================= Q conv: 128x128 tile, BK=32, 32KB LDS
__global__ __launch_bounds__(256) void conv128_fwd(
    const us* __restrict__ inT, const us* __restrict__ wp,
    us* __restrict__ out, int Cout) {
  __shared__ __align__(16) us sh[2][8192];    // [buf][A 128x32 | B 128x32] 32 KB
  int bid = blockIdx.x;                       // 512 blocks
  int v = (bid & 7) * 64 + (bid >> 3);        // chunked XCD swizzle
  int pxt = v & 31, cot = (v >> 5) & 7, b = v >> 8;
  int p0 = pxt * 128, co0 = cot * 128;
  int tid = threadIdx.x;
  int wave = tid >> 6, lane = tid & 63, l15 = lane & 15, hi4 = lane >> 4;
  int wr = wave >> 1, wc = wave & 1;
  f32x4 acc[4][4];
#pragma unroll
  for (int m = 0; m < 4; ++m)
#pragma unroll
    for (int n = 0; n < 4; ++n) acc[m][n] = (f32x4){0.f, 0.f, 0.f, 0.f};

  // staging: per thread 2 A-loads + 2 B-loads; row = c*64 + wave*16 + (lane>>2)
  int arow[2], brow[2];
#pragma unroll
  for (int c = 0; c < 2; ++c) {
    int row = c * 64 + wave * 16 + (lane >> 2);
    int sg = (lane & 3) ^ ((row >> 1) & 3);
    int px = p0 + row;
    int y = px >> 6, xx = px & 63;
    arow[c] = (y * 66 + xx) * 512 + sg * 8;
    brow[c] = (co0 + row) * 512 + sg * 8;
  }
  int aoff[4], boff[4];
#pragma unroll
  for (int m = 0; m < 4; ++m) {
    int ra = wr * 64 + m * 16 + l15;
    int rb = wc * 64 + m * 16 + l15;
    aoff[m] = ra * 32 + ((hi4 ^ ((ra >> 1) & 3)) * 8);
    boff[m] = rb * 32 + ((hi4 ^ ((rb >> 1) & 3)) * 8);
  }
  const us* abase = inT + (size_t)b * 66 * 66 * 512;

  auto stage = [&](int buf, int t, int ci) {
    int ky = (t * 11) >> 5, kx = t - ky * 3;
    const us* as = abase + (ky * 66 + kx) * 512 + ci;
    const us* bs = wp + (size_t)t * Cout * 512 + ci;
    us* la = &sh[buf][0];
    us* lb = la + 4096;
#pragma unroll
    for (int c = 0; c < 2; ++c) {
      gload16(as + arow[c], la + (c * 64 + wave * 16) * 32);
      gload16(bs + brow[c], lb + (c * 64 + wave * 16) * 32);
    }
  };

  stage(0, 0, 0);
  __syncthreads();
  for (int cc = 0; cc < 16; ++cc) {
#pragma unroll
    for (int t = 0; t < 9; ++t) {
      int s = cc * 9 + t;
      int cur = s & 1;
      if (s < 143) {
        int tn = (t == 8) ? 0 : t + 1;
        int cn = (t == 8) ? (cc + 1) << 5 : cc << 5;
        stage(cur ^ 1, tn, cn);
      }
      const us* la = &sh[cur][0];
      const us* lb = la + 4096;
      short8 af[4], bf[4];
#pragma unroll
      for (int m = 0; m < 4; ++m) af[m] = *(const short8*)(la + aoff[m]);
#pragma unroll
      for (int n = 0; n < 4; ++n) bf[n] = *(const short8*)(lb + boff[n]);
#pragma unroll
      for (int m = 0; m < 4; ++m)
#pragma unroll
        for (int n = 0; n < 4; ++n)
          acc[m][n] = __builtin_amdgcn_mfma_f32_16x16x32_bf16(af[m], bf[n], acc[m][n], 0, 0, 0);
      __syncthreads();
    }
  }
  // RoPE epilogue: pairs (2j,2j+1) along co sit in adjacent lanes
  int par = lane & 1;
#pragma unroll
  for (int n = 0; n < 4; ++n) {
    int co = co0 + wc * 64 + n * 16 + l15;
    int j = (co & 127) >> 1;
    float th = exp2f(-(float)j * 0.20762050593f);  // 10000^(-j/64)
    float sth, cth;
    fsincos(th, &sth, &cth);
#pragma unroll
    for (int m = 0; m < 4; ++m) {
      int pxb = p0 + wr * 64 + m * 16 + hi4 * 4;
      float s0, c0;
      fsincos((float)pxb * th, &s0, &c0);
#pragma unroll
      for (int r = 0; r < 4; ++r) {
        float xv = acc[m][n][r];
        float ov = __shfl_xor(xv, 1);
        float y = par ? fmaf(ov, s0, xv * c0) : fmaf(xv, c0, -ov * s0);
        out[((size_t)b * 4096 + (pxb + r)) * Cout + co] = f2bf(y);
        float c1 = c0 * cth - s0 * sth;       // rotate angle by th (px+1)
        s0 = fmaf(c0, sth, s0 * cth);
        c0 = c1;
      }
    }
  }
}

// ================================================= 64^2 conv body (K,V), BK=32, 16KB LDS
template <int TRANS_OUT, int ROPE>
__device__ __forceinline__ void conv64_body(
    const us* __restrict__ inT, const us* __restrict__ wp,
    us* __restrict__ out, int Cout, int logCoT, int bid, int ngrid, us* sh) {
  int nchunk = ngrid >> 3;
  int v = (bid & 7) * nchunk + (bid >> 3);
  int yt = v & 15;
  int cot = (v >> 4) & ((1 << logCoT) - 1);
  int b = v >> (4 + logCoT);
  int p0 = yt * 64, co0 = cot * 64;
  const int W = 32, logW = 5, padW = 34, HW = 1024;
  int tid = threadIdx.x;
  int wave = tid >> 6, lane = tid & 63, l15 = lane & 15, hi4 = lane >> 4;
  f32x4 acc[4];
#pragma unroll
  for (int i = 0; i < 4; ++i) acc[i] = (f32x4){0.f, 0.f, 0.f, 0.f};

  int arow0, brow0;
  {
    int row = wave * 16 + (lane >> 2);
    int sg = (lane & 3) ^ ((row >> 1) & 3);
    int px = p0 + row;
    int y = px >> logW, xx = px & (W - 1);
    arow0 = (y * padW + xx) * 512 + sg * 8;
    brow0 = (co0 + row) * 512 + sg * 8;
  }
  int aoff[4], boff0;
#pragma unroll
  for (int i = 0; i < 4; ++i) {
    int ra = i * 16 + l15;
    aoff[i] = ra * 32 + ((hi4 ^ ((ra >> 1) & 3)) * 8);
  }
  {
    int rb = 16 * wave + l15;
    boff0 = rb * 32 + ((hi4 ^ ((rb >> 1) & 3)) * 8);
  }
  const us* abase = inT + (size_t)b * padW * padW * 512;

  auto stage = [&](int buf, int t, int ci) {
    int ky = (t * 11) >> 5, kx = t - ky * 3;
    const us* as = abase + (ky * padW + kx) * 512 + ci;
    const us* bs = wp + (size_t)t * Cout * 512 + ci;
    us* la = sh + buf * 4096;
    us* lb = la + 2048;
    gload16(as + arow0, la + (wave * 16) * 32);
    gload16(bs + brow0, lb + (wave * 16) * 32);
  };

  stage(0, 0, 0);
  __syncthreads();
  for (int cc = 0; cc < 16; ++cc) {
#pragma unroll
    for (int t = 0; t < 9; ++t) {
      int s = cc * 9 + t;
      int cur = s & 1;
      if (s < 143) {
        int tn = (t == 8) ? 0 : t + 1;
        int cn = (t == 8) ? (cc + 1) << 5 : cc << 5;
        stage(cur ^ 1, tn, cn);
      }
      const us* la = sh + cur * 4096;
      const us* lb = la + 2048;
      short8 bf = *(const short8*)(lb + boff0);
#pragma unroll
      for (int i = 0; i < 4; ++i) {
        short8 af = *(const short8*)(la + aoff[i]);
        acc[i] = __builtin_amdgcn_mfma_f32_16x16x32_bf16(af, bf, acc[i], 0, 0, 0);
      }
      __syncthreads();
    }
  }
  if (ROPE) {
    int co = co0 + 16 * wave + l15;
    int j = (co & 127) >> 1;
    float th = exp2f(-(float)j * 0.20762050593f);
    float sth, cth;
    fsincos(th, &sth, &cth);
    int par = lane & 1;
#pragma unroll
    for (int i = 0; i < 4; ++i) {
      int pxb = p0 + i * 16 + hi4 * 4;
      float s0, c0;
      fsincos((float)pxb * th, &s0, &c0);
#pragma unroll
      for (int r = 0; r < 4; ++r) {
        float xv = acc[i][r];
        float ov = __shfl_xor(xv, 1);
        float y = par ? fmaf(ov, s0, xv * c0) : fmaf(xv, c0, -ov * s0);
        out[((size_t)b * HW + (pxb + r)) * Cout + co] = f2bf(y);
        float c1 = c0 * cth - s0 * sth;
        s0 = fmaf(c0, sth, s0 * cth);
        c0 = c1;
      }
    }
  } else {
#pragma unroll
    for (int i = 0; i < 4; ++i)
#pragma unroll
      for (int r = 0; r < 4; ++r) {
        int px = TRANS_OUT ? (p0 + (hi4 * 4 + r) * 4 + i)  // sigma(k)=(k%16)*4+k/16
                           : (p0 + i * 16 + hi4 * 4 + r);
        int co = co0 + 16 * wave + l15;
        us val = f2bf(acc[i][r]);
        if (TRANS_OUT)
          out[((size_t)b * Cout + co) * HW + px] = val;
        else
          out[((size_t)b * HW + px) * Cout + co] = val;
      }
  }
}

__global__ __launch_bounds__(256) void conv64_all(
    const us* __restrict__ cpadT, const us* __restrict__ wkp,
    const us* __restrict__ wvp, us* __restrict__ kb, us* __restrict__ vT) {
  __shared__ __align__(16) us sh[2][4096];  // 16 KB
  int bid = blockIdx.x;
  if (bid < 256) conv64_body<0, 1>(cpadT, wkp, kb, 512, 3, bid, 256, &sh[0][0]);
  else           conv64_body<1, 0>(cpadT, wvp, vT, 256, 2, bid - 256, 128, &sh[0][0]);
}

// ================================================= final conv: 128co x 64px, BK=32, 24KB LDS
__global__ __launch_bounds__(256) void conv128_out(
    const us* __restrict__ apad, const us* __restrict__ wp,
    float* __restrict__ out) {
  __shared__ __align__(16) us lds[2][6144];    // [buf][A 128x32 | B 64x32]
  int bid = blockIdx.x;                        // 512 blocks
  int v = (bid & 7) * 64 + (bid >> 3);         // chunked XCD swizzle
  int pxt = v & 63, cot = (v >> 6) & 3, b = v >> 8;
  int p0 = pxt * 64, co0 = cot * 128;
  int tid = threadIdx.x;
  int wave = tid >> 6, lane = tid & 63, l15 = lane & 15, hi4 = lane >> 4;
  int wr = wave >> 1, wc = wave & 1;
  f32x4 acc[4][2];
#pragma unroll
  for (int m = 0; m < 4; ++m)
#pragma unroll
    for (int n = 0; n < 2; ++n) acc[m][n] = (f32x4){0.f, 0.f, 0.f, 0.f};

  int arow[2], brow0;
#pragma unroll
  for (int c = 0; c < 2; ++c) {
    int row = c * 64 + wave * 16 + (lane >> 2);
    int sg = (lane & 3) ^ ((row >> 1) & 3);
    arow[c] = (co0 + row) * 512 + sg * 8;      // weight rows (co)
  }
  {
    int row = wave * 16 + (lane >> 2);
    int sg = (lane & 3) ^ ((row >> 1) & 3);
    int px = p0 + row;
    int y = px >> 6, xx = px & 63;
    brow0 = (y * 66 + xx) * 512 + sg * 8;      // pixel rows
  }
  int aoff[4], boff[2];
#pragma unroll
  for (int m = 0; m < 4; ++m) {
    int ra = wr * 64 + m * 16 + l15;
    aoff[m] = ra * 32 + ((hi4 ^ ((ra >> 1) & 3)) * 8);
  }
#pragma unroll
  for (int n = 0; n < 2; ++n) {
    int rb = wc * 32 + n * 16 + l15;
    boff[n] = rb * 32 + ((hi4 ^ ((rb >> 1) & 3)) * 8);
  }
  const us* bbase = apad + (size_t)b * 4356 * 512;

  auto stage = [&](int buf, int t, int ci) {
    int ky = (t * 11) >> 5, kx = t - ky * 3;
    const us* as = wp + (size_t)t * 512 * 512 + ci;
    const us* bs = bbase + (ky * 66 + kx) * 512 + ci;
    us* la = &lds[buf][0];
    us* lb = la + 4096;
#pragma unroll
    for (int c = 0; c < 2; ++c)
      gload16(as + arow[c], la + (c * 64 + wave * 16) * 32);
    gload16(bs + brow0, lb + (wave * 16) * 32);
  };

  stage(0, 0, 0);
  __syncthreads();
  for (int cc = 0; cc < 16; ++cc) {
#pragma unroll
    for (int t = 0; t < 9; ++t) {
      int s = cc * 9 + t;
      int cur = s & 1;
      if (s < 143) {
        int tn = (t == 8) ? 0 : t + 1;
        int cn = (t == 8) ? (cc + 1) << 5 : cc << 5;
        stage(cur ^ 1, tn, cn);
      }
      const us* la = &lds[cur][0];
      const us* lb = la + 4096;
      short8 af[4], bf[2];
#pragma unroll
      for (int m = 0; m < 4; ++m) af[m] = *(const short8*)(la + aoff[m]);
#pragma unroll
      for (int n = 0; n < 2; ++n) bf[n] = *(const short8*)(lb + boff[n]);
#pragma unroll
      for (int m = 0; m < 4; ++m)
#pragma unroll
        for (int n = 0; n < 2; ++n)
          acc[m][n] = __builtin_amdgcn_mfma_f32_16x16x32_bf16(af[m], bf[n], acc[m][n], 0, 0, 0);
      __syncthreads();
    }
  }
#pragma unroll
  for (int m = 0; m < 4; ++m)
#pragma unroll
    for (int n = 0; n < 2; ++n)
#pragma unroll
      for (int r = 0; r < 4; ++r) {
        int co = co0 + wr * 64 + m * 16 + hi4 * 4 + r;
        int px = p0 + wc * 32 + n * 16 + l15;
        out[((size_t)b * 512 + co) * 4096 + px] = acc[m][n][r];
      }
}

// ================================================= differential GQA attention + RMSNorm
// QBLK=64 (grid 1024 -> 3 blocks/CU); R7 sync structure (vmcnt(6), 2 barriers).
__global__ __launch_bounds__(256) void attn_kernel(
    const us* __restrict__ qb, const us* __restrict__ kb,
    const us* __restrict__ vT, const float* __restrict__ lam,
    us* __restrict__ apad) {
  int qt = blockIdx.x, h = blockIdx.y, b = blockIdx.z;
  int kvh = h >> 1;
  int tid = threadIdx.x;
  int wave = tid >> 6, lane = tid & 63, l15 = lane & 15, hi4 = lane >> 4;
  __shared__ __align__(16) us Klds[2][8192];   // [buf][64 k rows][128 d]
  __shared__ __align__(16) us Vlds[2][4096];   // [buf][64 dv rows][64 k']
  __shared__ __align__(16) us Plds[4][16][72];

  int q0 = qt * 64;
  short8 qf[2][2];  // [m][ks]
  {
    const us* qsrc =
        qb + ((size_t)(b * 4096 + q0 + wave * 16 + l15)) * 1024 + h * 128 + hi4 * 8;
#pragma unroll
    for (int m = 0; m < 2; ++m)
#pragma unroll
      for (int ks = 0; ks < 2; ++ks)
        qf[m][ks] = *(const short8*)(qsrc + m * 64 + ks * 32);
  }

  float sumd[2][4];
  f32x4 accO[2][4];
#pragma unroll
  for (int m = 0; m < 2; ++m)
#pragma unroll
    for (int r = 0; r < 4; ++r) {
      sumd[m][r] = 0.f;
      accO[m][r] = (f32x4){0.f, 0.f, 0.f, 0.f};
    }
  float lamh = lam[h];

  const us* kbase0 = kb + (size_t)b * 524288 + kvh * 128;
  const us* vbase0 = vT + ((size_t)(b * 256 + kvh * 64)) * 1024;
  int krow[4], vrow[2];
#pragma unroll
  for (int c = 0; c < 4; ++c) {
    int row = (wave * 4 + c) * 4 + hi4;
    int g = (l15 & 8) | ((l15 & 7) ^ (row & 7));
    krow[c] = row * 512 + g * 8;
  }
#pragma unroll
  for (int c = 0; c < 2; ++c) {
    int row = (wave * 2 + c) * 8 + (lane >> 3);
    int g = (lane & 7) ^ (row & 7);
    vrow[c] = row * 1024 + g * 8;
  }
  int kg0[2], kg1[2], vg[2];
#pragma unroll
  for (int m = 0; m < 2; ++m) {
    kg0[m] = (m * 8 | (hi4 ^ (l15 & 7))) * 8;
    kg1[m] = (m * 8 | ((4 + hi4) ^ (l15 & 7))) * 8;
  }
#pragma unroll
  for (int ks = 0; ks < 2; ++ks) vg[ks] = ((ks * 4 + hi4) ^ (l15 & 7)) * 8;

  auto stage = [&](int buf, int kt2) {
    const us* kk = kbase0 + (size_t)kt2 * 32768;
    const us* vv = vbase0 + kt2 * 64;
#pragma unroll
    for (int c = 0; c < 4; ++c)
      gload16(kk + krow[c], &Klds[buf][(wave * 4 + c) * 512]);
#pragma unroll
    for (int c = 0; c < 2; ++c)
      gload16(vv + vrow[c], &Vlds[buf][(wave * 2 + c) * 512]);
  };

  const float cexp = 0.18033688f;  // 0.125 * log2(e)
  stage(0, 0);
  for (int kt = 0; kt < 16; ++kt) {
    int cur = kt & 1;
    if (kt < 15) {
      stage(cur ^ 1, kt + 1);
      asm volatile("s_waitcnt vmcnt(6)" ::: "memory");
    } else {
      asm volatile("s_waitcnt vmcnt(0)" ::: "memory");
    }
    __builtin_amdgcn_s_barrier();
    __builtin_amdgcn_sched_barrier(0);

    short8 vf[2][4];
#pragma unroll
    for (int ks = 0; ks < 2; ++ks)
#pragma unroll
      for (int nf = 0; nf < 4; ++nf)
        vf[ks][nf] = *(const short8*)&Vlds[cur][(nf * 16 + l15) * 64 + vg[ks]];

#pragma unroll
    for (int m = 0; m < 2; ++m) {
      short8 kf[4][2];
#pragma unroll
      for (int nf = 0; nf < 4; ++nf) {
        kf[nf][0] = *(const short8*)&Klds[cur][(nf * 16 + l15) * 128 + kg0[m]];
        kf[nf][1] = *(const short8*)&Klds[cur][(nf * 16 + l15) * 128 + kg1[m]];
      }
      f32x4 s[4];
      __builtin_amdgcn_s_setprio(1);
#pragma unroll
      for (int nf = 0; nf < 4; ++nf) {
        f32x4 z = (f32x4){0.f, 0.f, 0.f, 0.f};
        z = __builtin_amdgcn_mfma_f32_16x16x32_bf16(qf[m][0], kf[nf][0], z, 0, 0, 0);
        z = __builtin_amdgcn_mfma_f32_16x16x32_bf16(qf[m][1], kf[nf][1], z, 0, 0, 0);
        s[nf] = z;
      }
      __builtin_amdgcn_s_setprio(0);
#pragma unroll
      for (int r = 0; r < 4; ++r) {
        float p0 = fast_exp2(s[0][r] * cexp);
        float p1 = fast_exp2(s[1][r] * cexp);
        float p2 = fast_exp2(s[2][r] * cexp);
        float p3 = fast_exp2(s[3][r] * cexp);
        sumd[m][r] += (p0 + p1) + (p2 + p3);
        unsigned int w0 = cvt_pk_bf16(p0, p1);
        unsigned int w1 = cvt_pk_bf16(p2, p3);
        *(uint2*)&Plds[wave][hi4 * 4 + r][l15 * 4] = make_uint2(w0, w1);
      }
      __builtin_amdgcn_s_setprio(1);
#pragma unroll
      for (int ks = 0; ks < 2; ++ks) {
        short8 pf = *(const short8*)&Plds[wave][l15][ks * 32 + hi4 * 8];
#pragma unroll
        for (int nf = 0; nf < 4; ++nf)
          accO[m][nf] =
              __builtin_amdgcn_mfma_f32_16x16x32_bf16(pf, vf[ks][nf], accO[m][nf], 0, 0, 0);
      }
      __builtin_amdgcn_s_setprio(0);
    }
    asm volatile("s_waitcnt lgkmcnt(0)" ::: "memory");
    __builtin_amdgcn_s_barrier();
    __builtin_amdgcn_sched_barrier(0);
  }

  // epilogue: denom reduce, combine mults, RMSNorm, scale 0.8
#pragma unroll
  for (int m = 0; m < 2; ++m)
#pragma unroll
    for (int r = 0; r < 4; ++r) {
      float sx = sumd[m][r];
      sx += __shfl_xor(sx, 1);
      sx += __shfl_xor(sx, 2);
      sx += __shfl_xor(sx, 4);
      sx += __shfl_xor(sx, 8);
      sumd[m][r] = sx;
    }
#pragma unroll
  for (int r = 0; r < 4; ++r) {
    float inv0 = 1.f / sumd[0][r];
    float inv1 = lamh / sumd[1][r];
    float comb[4];
    float ss = 0.f;
#pragma unroll
    for (int nf = 0; nf < 4; ++nf) {
      comb[nf] = accO[0][nf][r] * inv0 + accO[1][nf][r] * inv1;
      ss += comb[nf] * comb[nf];
    }
    ss += __shfl_xor(ss, 1);
    ss += __shfl_xor(ss, 2);
    ss += __shfl_xor(ss, 4);
    ss += __shfl_xor(ss, 8);
    float sc = rsqrtf(ss * (1.f / 64.f) + 1e-8f) * 0.8f;
    int q = q0 + wave * 16 + hi4 * 4 + r;
    int y = q >> 6, x = q & 63;
    size_t oaddr = ((size_t)b * 4356 + (size_t)(y + 1) * 66 + (x + 1)) * 512 + h * 64;
#pragma unroll
    for (int nf = 0; nf < 4; ++nf) apad[oaddr + nf * 16 + l15] = f2bf(comb[nf] * sc);
  }
}

// ============================================================== launch
extern "C" void kernel_launch(void* const* d_in, const int* in_sizes, int n_in,
                              void* d_out, int out_size, void* d_ws, size_t ws_size,
                              hipStream_t stream) {
  const float* x     = (const float*)d_in[0];
  const float* cross = (const float*)d_in[1];
  const float* wq    = (const float*)d_in[2];
  const float* wk    = (const float*)d_in[3];
  const float* wv    = (const float*)d_in[4];
  const float* wo    = (const float*)d_in[5];
  const float* lq1   = (const float*)d_in[6];
  const float* lq2   = (const float*)d_in[7];
  const float* lk1   = (const float*)d_in[8];
  const float* lk2   = (const float*)d_in[9];
  float* out = (float*)d_out;

  char* ws = (char*)d_ws;
  size_t off = 0;
  auto nxt = [&](size_t bytes) { char* p = ws + off; off += bytes; return p; };
  us* xpadT = (us*)nxt(8921088);   // [2][4356][512] bf16
  us* cpadT = (us*)nxt(2367488);   // [2][1156][512] bf16
  us* apad  = (us*)nxt(8921088);   // [2][4356][512] bf16
  us* wqp = (us*)nxt(9437184);     // [9][1024][512]
  us* wkp = (us*)nxt(4718592);     // [9][512][512]
  us* wvp = (us*)nxt(2359296);     // [9][256][512]
  us* wop = (us*)nxt(4718592);     // [9][512][512]
  us* qb  = (us*)nxt(16777216);    // [2][4096][1024] (rope'd)
  us* kb  = (us*)nxt(2097152);     // [2][1024][512]  (rope'd)
  us* vT  = (us*)nxt(1048576);     // [2][256][1024] (sigma-permuted along k)
  float* lam = (float*)nxt(256);   // [8]
  (void)ws_size; (void)in_sizes; (void)n_in; (void)out_size;

  prep_all<<<4167, 256, 0, stream>>>(x, cross, wq, wk, wv, wo,
                                     lq1, lq2, lk1, lk2,
                                     xpadT, cpadT, apad, wqp, wkp, wvp, wop, lam);
  conv128_fwd<<<512, 256, 0, stream>>>(xpadT, wqp, qb, 1024);
  conv64_all<<<384, 256, 0, stream>>>(cpadT, wkp, wvp, kb, vT);
  attn_kernel<<<dim3(64, 8, 2), 256, 0, stream>>>(qb, kb, vT, lam, apad);
  conv128_out<<<512, 256, 0, stream>>>(apad, wop, out);
}

// Round 14
// 222.688 us; speedup vs baseline: 1.1607x; 1.1607x over previous
//
#include <hip/hip_runtime.h>

// ConvCrossAttention on MI355X (gfx950), bf16 MFMA implementation.
// R14 = R12 revert (best known: 222.6 us). R13's BK=32 regressed (-16 us on
// Q-conv: doubled barrier count outweighed occupancy; LDS size was not the
// occupancy limiter). BK=64 is the optimum of the 2-barrier dbuf skeleton.

typedef __attribute__((ext_vector_type(8))) short short8;
typedef __attribute__((ext_vector_type(4))) float f32x4;
typedef unsigned short us;

__device__ __forceinline__ float bf2f(us u) {
  union { unsigned int i; float f; } v; v.i = ((unsigned int)u) << 16; return v.f;
}
__device__ __forceinline__ us f2bf(float f) {
  union { float f; unsigned int i; } v; v.f = f;
  unsigned int x = v.i;
  return (us)((x + 0x7fffu + ((x >> 16) & 1u)) >> 16);
}

typedef __attribute__((address_space(3))) unsigned int as3_uint;
typedef const __attribute__((address_space(1))) unsigned int as1_uint;
__device__ __forceinline__ void gload16(const us* g, us* l) {
  __builtin_amdgcn_global_load_lds((as1_uint*)g, (as3_uint*)l, 16, 0, 0);
}
__device__ __forceinline__ unsigned int cvt_pk_bf16(float a, float b) {
  unsigned int r;
  asm("v_cvt_pk_bf16_f32 %0, %1, %2" : "=v"(r) : "v"(a), "v"(b));
  return r;
}
__device__ __forceinline__ float fast_exp2(float x) {
  float r;
  asm("v_exp_f32 %0, %1" : "=v"(r) : "v"(x));
  return r;
}
// sin/cos via HW transcendentals (input: revolutions, fract-reduced).
__device__ __forceinline__ void fsincos(float ang, float* sn, float* cs) {
  float r = ang * 0.15915494309f;
  r = r - floorf(r);
  float s, c;
  asm("v_sin_f32 %0, %1" : "=v"(s) : "v"(r));
  asm("v_cos_f32 %0, %1" : "=v"(c) : "v"(r));
  *sn = s; *cs = c;
}

// ================================================= fused prep kernel
__device__ __forceinline__ void transpose_body(
    const float* __restrict__ in, us* __restrict__ outT,
    int b, int y, int ci0, int H, int W, int logW) {
  const int C = 512;
  int padW = W + 2, Ppad = (H + 2) * padW;
  __shared__ float tile[64][65];
  int nt = W * 64;
  for (int idx = threadIdx.x; idx < nt; idx += 256) {
    int ci = idx >> logW, x = idx & (W - 1);
    tile[ci][x] = in[(((size_t)b * C + ci0 + ci) * H + y) * W + x];
  }
  __syncthreads();
  int nt2 = W * 32;
  for (int idx = threadIdx.x; idx < nt2; idx += 256) {
    int px = idx >> 5, c2 = idx & 31;
    unsigned int val = (unsigned int)f2bf(tile[c2 * 2][px]) |
                       ((unsigned int)f2bf(tile[c2 * 2 + 1][px]) << 16);
    *(unsigned int*)(outT + ((size_t)b * Ppad + (size_t)(y + 1) * padW + (px + 1)) * C +
                     ci0 + c2 * 2) = val;
  }
}

__global__ __launch_bounds__(256) void prep_all(
    const float* __restrict__ x, const float* __restrict__ cross,
    const float* __restrict__ wq, const float* __restrict__ wk,
    const float* __restrict__ wv, const float* __restrict__ wo,
    const float* __restrict__ lq1, const float* __restrict__ lq2,
    const float* __restrict__ lk1, const float* __restrict__ lk2,
    us* __restrict__ xpadT, us* __restrict__ cpadT, us* __restrict__ apad,
    us* __restrict__ oq, us* __restrict__ ok, us* __restrict__ ov,
    us* __restrict__ oo, float* __restrict__ lam) {
  int bid = blockIdx.x, tid = threadIdx.x;
  if (bid < 326) {
    int g = bid * 4 + (tid >> 6);
    int t = tid & 63;
    us* base; int W, b, i;
    if (g < 520)      { base = xpadT; W = 64; b = g >= 260; i = g - b * 260; }
    else if (g < 784) { base = cpadT; W = 32; int gg = g - 520; b = gg >= 132; i = gg - b * 132; }
    else              { base = apad; W = 64; int gg = g - 784; b = gg >= 260; i = gg - b * 260; }
    int padW = W + 2, nb = 2 * padW;
    int yy, xx;
    if (i < padW)    { yy = 0; xx = i; }
    else if (i < nb) { yy = W + 1; xx = i - padW; }
    else             { int j = i - nb; yy = 1 + (j >> 1); xx = (j & 1) * (W + 1); }
    size_t p = ((size_t)b * padW * padW + (size_t)yy * padW + xx) * 512 + t * 8;
    *(int4*)(base + p) = make_int4(0, 0, 0, 0);
  } else if (bid < 1350) {
    int i = bid - 326;
    transpose_body(x, xpadT, i >> 9, (i >> 3) & 63, (i & 7) * 64, 64, 64, 6);
  } else if (bid < 1862) {
    int i = bid - 1350;
    transpose_body(cross, cpadT, i >> 8, (i >> 3) & 31, (i & 7) * 64, 32, 32, 5);
  } else if (bid < 4166) {
    int blk = bid - 1862;
    const float* src; us* dst; int Cout, co;
    if (blk < 1024)      { src = wq; dst = oq; Cout = 1024; co = blk; }
    else if (blk < 1536) { src = wk; dst = ok; Cout = 512;  co = blk - 1024; }
    else if (blk < 1792) { src = wv; dst = ov; Cout = 256;  co = blk - 1536; }
    else                 { src = wo; dst = oo; Cout = 512;  co = blk - 1792; }
    __shared__ us l[4608];
    const float* s0 = src + (size_t)co * 4608;
#pragma unroll
    for (int k = 0; k < 18; ++k) { int i = k * 256 + tid; l[i] = f2bf(s0[i]); }
    __syncthreads();
#pragma unroll
    for (int k = 0; k < 9; ++k) {
      int j = k * 256 + tid;
      int t = j >> 8, c2 = j & 255;
      unsigned int val = (unsigned int)l[(c2 * 2) * 9 + t] |
                         ((unsigned int)l[(c2 * 2 + 1) * 9 + t] << 16);
      *(unsigned int*)(dst + (size_t)t * Cout * 512 + (size_t)co * 512 + c2 * 2) = val;
    }
  } else {
    int h = tid >> 5, d = tid & 31;
    float s1 = lq1[h * 64 + d] * lk1[h * 64 + d] +
               lq1[h * 64 + d + 32] * lk1[h * 64 + d + 32];
    float s2 = lq2[h * 64 + d] * lk2[h * 64 + d] +
               lq2[h * 64 + d + 32] * lk2[h * 64 + d + 32];
    for (int m = 16; m; m >>= 1) {
      s1 += __shfl_xor(s1, m);
      s2 += __shfl_xor(s2, m);
    }
    if (d == 0) lam[h] = -(expf(s1) - expf(s2) + 0.2f);
  }
}

// ================================================= Q conv: 128x128 tile, dbuf, rope'd epilogue
// Loop order: ci-chunk OUTER, tap INNER (9-tap pixel-strip reuse stays L2-hot).
__global__ __launch_bounds__(256) void conv128_fwd(
    const us* __restrict__ inT, const us* __restrict__ wp,
    us* __restrict__ out, int Cout) {
  __shared__ __align__(16) us sh[2][2][128][64];   // 64 KB
  int bid = blockIdx.x;                       // 512 blocks
  int v = (bid & 7) * 64 + (bid >> 3);        // chunked XCD swizzle
  int pxt = v & 31, cot = (v >> 5) & 7, b = v >> 8;
  int p0 = pxt * 128, co0 = cot * 128;
  int tid = threadIdx.x;
  int wave = tid >> 6, lane = tid & 63, l15 = lane & 15, hi4 = lane >> 4;
  int wr = wave >> 1, wc = wave & 1;
  f32x4 acc[4][4];
#pragma unroll
  for (int m = 0; m < 4; ++m)
#pragma unroll
    for (int n = 0; n < 4; ++n) acc[m][n] = (f32x4){0.f, 0.f, 0.f, 0.f};

  int arow[4], brow[4];
#pragma unroll
  for (int c = 0; c < 4; ++c) {
    int row = c * 32 + (tid >> 3);
    int g = (tid & 7) ^ (row & 7);
    int px = p0 + row;
    int y = px >> 6, x = px & 63;
    arow[c] = (y * 66 + x) * 512 + g * 8;
    brow[c] = (co0 + row) * 512 + g * 8;
  }
  int aoff[4][2], boff[4][2];
#pragma unroll
  for (int m = 0; m < 4; ++m)
#pragma unroll
    for (int ks = 0; ks < 2; ++ks) {
      int ra = wr * 64 + m * 16 + l15;
      int rb = wc * 64 + m * 16 + l15;
      aoff[m][ks] = ra * 64 + (((ks * 4 + hi4) ^ (l15 & 7)) * 8);
      boff[m][ks] = rb * 64 + (((ks * 4 + hi4) ^ (l15 & 7)) * 8);
    }
  const us* abase = inT + (size_t)b * 66 * 66 * 512;

  auto stage = [&](int buf, int t, int ci) {
    int ky = (t * 11) >> 5, kx = t - ky * 3;
    const us* as = abase + (ky * 66 + kx) * 512 + ci;
    const us* bs = wp + (size_t)t * Cout * 512 + ci;
    us* la = &sh[buf][0][0][0];
    us* lb = &sh[buf][1][0][0];
#pragma unroll
    for (int c = 0; c < 4; ++c) {
      gload16(as + arow[c], la + c * 2048 + wave * 512);
      gload16(bs + brow[c], lb + c * 2048 + wave * 512);
    }
  };

  stage(0, 0, 0);
  __syncthreads();
  for (int cc = 0; cc < 8; ++cc) {
#pragma unroll
    for (int t = 0; t < 9; ++t) {
      int s = cc * 9 + t;
      int cur = s & 1;
      if (s < 71) {
        int tn = (t == 8) ? 0 : t + 1;
        int cn = (t == 8) ? (cc + 1) << 6 : cc << 6;
        stage(cur ^ 1, tn, cn);
      }
      const us* la = &sh[cur][0][0][0];
      const us* lb = &sh[cur][1][0][0];
#pragma unroll
      for (int ks = 0; ks < 2; ++ks) {
        short8 af[4], bf[4];
#pragma unroll
        for (int m = 0; m < 4; ++m) af[m] = *(const short8*)(la + aoff[m][ks]);
#pragma unroll
        for (int n = 0; n < 4; ++n) bf[n] = *(const short8*)(lb + boff[n][ks]);
#pragma unroll
        for (int m = 0; m < 4; ++m)
#pragma unroll
          for (int n = 0; n < 4; ++n)
            acc[m][n] = __builtin_amdgcn_mfma_f32_16x16x32_bf16(af[m], bf[n], acc[m][n], 0, 0, 0);
      }
      __syncthreads();
    }
  }
  // RoPE epilogue: pairs (2j,2j+1) along co sit in adjacent lanes
  int par = lane & 1;
#pragma unroll
  for (int n = 0; n < 4; ++n) {
    int co = co0 + wc * 64 + n * 16 + l15;
    int j = (co & 127) >> 1;
    float th = exp2f(-(float)j * 0.20762050593f);  // 10000^(-j/64)
    float sth, cth;
    fsincos(th, &sth, &cth);
#pragma unroll
    for (int m = 0; m < 4; ++m) {
      int pxb = p0 + wr * 64 + m * 16 + hi4 * 4;
      float s0, c0;
      fsincos((float)pxb * th, &s0, &c0);
#pragma unroll
      for (int r = 0; r < 4; ++r) {
        float xv = acc[m][n][r];
        float ov = __shfl_xor(xv, 1);
        float y = par ? fmaf(ov, s0, xv * c0) : fmaf(xv, c0, -ov * s0);
        out[((size_t)b * 4096 + (pxb + r)) * Cout + co] = f2bf(y);
        float c1 = c0 * cth - s0 * sth;       // rotate angle by th (px+1)
        s0 = fmaf(c0, sth, s0 * cth);
        c0 = c1;
      }
    }
  }
}

// ================================================= 64^2 conv body (K,V), 32KB LDS
template <int TRANS_OUT, int ROPE>
__device__ __forceinline__ void conv64_body(
    const us* __restrict__ inT, const us* __restrict__ wp,
    us* __restrict__ out, int Cout, int logCoT, int bid, int ngrid, us* sh) {
  int nchunk = ngrid >> 3;
  int v = (bid & 7) * nchunk + (bid >> 3);
  int yt = v & 15;
  int cot = (v >> 4) & ((1 << logCoT) - 1);
  int b = v >> (4 + logCoT);
  int p0 = yt * 64, co0 = cot * 64;
  const int W = 32, logW = 5, padW = 34, HW = 1024;
  int tid = threadIdx.x;
  int wave = tid >> 6, lane = tid & 63, l15 = lane & 15, hi4 = lane >> 4;
  f32x4 acc[4];
#pragma unroll
  for (int i = 0; i < 4; ++i) acc[i] = (f32x4){0.f, 0.f, 0.f, 0.f};

  int arow[2], brow[2];
#pragma unroll
  for (int c = 0; c < 2; ++c) {
    int row = (wave * 2 + c) * 8 + (lane >> 3);
    int g = (lane & 7) ^ (row & 7);
    int px = p0 + row;
    int y = px >> logW, x = px & (W - 1);
    arow[c] = (y * padW + x) * 512 + g * 8;
    brow[c] = (co0 + row) * 512 + g * 8;
  }
  int gb[2];
#pragma unroll
  for (int ks = 0; ks < 2; ++ks) gb[ks] = ((ks * 4 + hi4) ^ (l15 & 7)) * 8;

  const us* abase = inT + (size_t)b * padW * padW * 512;

  auto stage = [&](int buf, int t, int ci) {
    int ky = (t * 11) >> 5, kx = t - ky * 3;
    const us* as = abase + (ky * padW + kx) * 512 + ci;
    const us* bs = wp + (size_t)t * Cout * 512 + ci;
    us* la = sh + buf * 8192;
    us* lb = la + 4096;
#pragma unroll
    for (int c = 0; c < 2; ++c) {
      gload16(as + arow[c], la + (wave * 2 + c) * 512);
      gload16(bs + brow[c], lb + (wave * 2 + c) * 512);
    }
  };

  stage(0, 0, 0);
  __syncthreads();
  for (int cc = 0; cc < 8; ++cc) {
#pragma unroll
    for (int t = 0; t < 9; ++t) {
      int s = cc * 9 + t;
      int cur = s & 1;
      if (s < 71) {
        int tn = (t == 8) ? 0 : t + 1;
        int cn = (t == 8) ? (cc + 1) << 6 : cc << 6;
        stage(cur ^ 1, tn, cn);
      }
      const us* la = sh + cur * 8192;
      const us* lb = la + 4096;
#pragma unroll
      for (int ks = 0; ks < 2; ++ks) {
        short8 bf = *(const short8*)(lb + (16 * wave + l15) * 64 + gb[ks]);
#pragma unroll
        for (int i = 0; i < 4; ++i) {
          short8 af = *(const short8*)(la + (i * 16 + l15) * 64 + gb[ks]);
          acc[i] = __builtin_amdgcn_mfma_f32_16x16x32_bf16(af, bf, acc[i], 0, 0, 0);
        }
      }
      __syncthreads();
    }
  }
  if (ROPE) {
    int co = co0 + 16 * wave + l15;
    int j = (co & 127) >> 1;
    float th = exp2f(-(float)j * 0.20762050593f);
    float sth, cth;
    fsincos(th, &sth, &cth);
    int par = lane & 1;
#pragma unroll
    for (int i = 0; i < 4; ++i) {
      int pxb = p0 + i * 16 + hi4 * 4;
      float s0, c0;
      fsincos((float)pxb * th, &s0, &c0);
#pragma unroll
      for (int r = 0; r < 4; ++r) {
        float xv = acc[i][r];
        float ov = __shfl_xor(xv, 1);
        float y = par ? fmaf(ov, s0, xv * c0) : fmaf(xv, c0, -ov * s0);
        out[((size_t)b * HW + (pxb + r)) * Cout + co] = f2bf(y);
        float c1 = c0 * cth - s0 * sth;
        s0 = fmaf(c0, sth, s0 * cth);
        c0 = c1;
      }
    }
  } else {
#pragma unroll
    for (int i = 0; i < 4; ++i)
#pragma unroll
      for (int r = 0; r < 4; ++r) {
        int px = TRANS_OUT ? (p0 + (hi4 * 4 + r) * 4 + i)  // sigma(k)=(k%16)*4+k/16
                           : (p0 + i * 16 + hi4 * 4 + r);
        int co = co0 + 16 * wave + l15;
        us val = f2bf(acc[i][r]);
        if (TRANS_OUT)
          out[((size_t)b * Cout + co) * HW + px] = val;
        else
          out[((size_t)b * HW + px) * Cout + co] = val;
      }
  }
}

__global__ __launch_bounds__(256) void conv64_all(
    const us* __restrict__ cpadT, const us* __restrict__ wkp,
    const us* __restrict__ wvp, us* __restrict__ kb, us* __restrict__ vT) {
  __shared__ __align__(16) us sh[2][2][64][64];  // 32 KB
  int bid = blockIdx.x;
  if (bid < 256) conv64_body<0, 1>(cpadT, wkp, kb, 512, 3, bid, 256, &sh[0][0][0][0]);
  else           conv64_body<1, 0>(cpadT, wvp, vT, 256, 2, bid - 256, 128, &sh[0][0][0][0]);
}

// ================================================= final conv: 128co x 64px tile, grid 512
__global__ __launch_bounds__(256) void conv128_out(
    const us* __restrict__ apad, const us* __restrict__ wp,
    float* __restrict__ out) {
  __shared__ __align__(16) us lds[2][12288];   // [buf][A 128x64 | B 64x64]
  int bid = blockIdx.x;                        // 512 blocks
  int v = (bid & 7) * 64 + (bid >> 3);         // chunked XCD swizzle
  int pxt = v & 63, cot = (v >> 6) & 3, b = v >> 8;
  int p0 = pxt * 64, co0 = cot * 128;
  int tid = threadIdx.x;
  int wave = tid >> 6, lane = tid & 63, l15 = lane & 15, hi4 = lane >> 4;
  int wr = wave >> 1, wc = wave & 1;
  f32x4 acc[4][2];
#pragma unroll
  for (int m = 0; m < 4; ++m)
#pragma unroll
    for (int n = 0; n < 2; ++n) acc[m][n] = (f32x4){0.f, 0.f, 0.f, 0.f};

  int arow[4], brow[2];
#pragma unroll
  for (int c = 0; c < 4; ++c) {
    int row = c * 32 + (tid >> 3);
    int g = (tid & 7) ^ (row & 7);
    arow[c] = (co0 + row) * 512 + g * 8;       // weight rows (co)
  }
#pragma unroll
  for (int c = 0; c < 2; ++c) {
    int row = c * 32 + (tid >> 3);
    int g = (tid & 7) ^ (row & 7);
    int px = p0 + row;
    int y = px >> 6, x = px & 63;
    brow[c] = (y * 66 + x) * 512 + g * 8;      // pixel rows
  }
  int aoff[4][2], boff[2][2];
#pragma unroll
  for (int m = 0; m < 4; ++m)
#pragma unroll
    for (int ks = 0; ks < 2; ++ks) {
      int ra = wr * 64 + m * 16 + l15;
      aoff[m][ks] = ra * 64 + (((ks * 4 + hi4) ^ (l15 & 7)) * 8);
    }
#pragma unroll
  for (int n = 0; n < 2; ++n)
#pragma unroll
    for (int ks = 0; ks < 2; ++ks) {
      int rb = wc * 32 + n * 16 + l15;
      boff[n][ks] = rb * 64 + (((ks * 4 + hi4) ^ (l15 & 7)) * 8);
    }
  const us* bbase = apad + (size_t)b * 4356 * 512;

  auto stage = [&](int buf, int t, int ci) {
    int ky = (t * 11) >> 5, kx = t - ky * 3;
    const us* as = wp + (size_t)t * 512 * 512 + ci;
    const us* bs = bbase + (ky * 66 + kx) * 512 + ci;
    us* la = &lds[buf][0];
    us* lb = la + 8192;
#pragma unroll
    for (int c = 0; c < 4; ++c)
      gload16(as + arow[c], la + c * 2048 + wave * 512);
#pragma unroll
    for (int c = 0; c < 2; ++c)
      gload16(bs + brow[c], lb + c * 2048 + wave * 512);
  };

  stage(0, 0, 0);
  __syncthreads();
  for (int cc = 0; cc < 8; ++cc) {
#pragma unroll
    for (int t = 0; t < 9; ++t) {
      int s = cc * 9 + t;
      int cur = s & 1;
      if (s < 71) {
        int tn = (t == 8) ? 0 : t + 1;
        int cn = (t == 8) ? (cc + 1) << 6 : cc << 6;
        stage(cur ^ 1, tn, cn);
      }
      const us* la = &lds[cur][0];
      const us* lb = la + 8192;
#pragma unroll
      for (int ks = 0; ks < 2; ++ks) {
        short8 af[4], bf[2];
#pragma unroll
        for (int m = 0; m < 4; ++m) af[m] = *(const short8*)(la + aoff[m][ks]);
#pragma unroll
        for (int n = 0; n < 2; ++n) bf[n] = *(const short8*)(lb + boff[n][ks]);
#pragma unroll
        for (int m = 0; m < 4; ++m)
#pragma unroll
          for (int n = 0; n < 2; ++n)
            acc[m][n] = __builtin_amdgcn_mfma_f32_16x16x32_bf16(af[m], bf[n], acc[m][n], 0, 0, 0);
      }
      __syncthreads();
    }
  }
#pragma unroll
  for (int m = 0; m < 4; ++m)
#pragma unroll
    for (int n = 0; n < 2; ++n)
#pragma unroll
      for (int r = 0; r < 4; ++r) {
        int co = co0 + wr * 64 + m * 16 + hi4 * 4 + r;
        int px = p0 + wc * 32 + n * 16 + l15;
        out[((size_t)b * 512 + co) * 4096 + px] = acc[m][n][r];
      }
}

// ================================================= differential GQA attention + RMSNorm
// QBLK=64 (grid 1024 -> 3 blocks/CU); R7 sync structure (vmcnt(6), 2 barriers).
__global__ __launch_bounds__(256) void attn_kernel(
    const us* __restrict__ qb, const us* __restrict__ kb,
    const us* __restrict__ vT, const float* __restrict__ lam,
    us* __restrict__ apad) {
  int qt = blockIdx.x, h = blockIdx.y, b = blockIdx.z;
  int kvh = h >> 1;
  int tid = threadIdx.x;
  int wave = tid >> 6, lane = tid & 63, l15 = lane & 15, hi4 = lane >> 4;
  __shared__ __align__(16) us Klds[2][8192];   // [buf][64 k rows][128 d]
  __shared__ __align__(16) us Vlds[2][4096];   // [buf][64 dv rows][64 k']
  __shared__ __align__(16) us Plds[4][16][72];

  int q0 = qt * 64;
  short8 qf[2][2];  // [m][ks]
  {
    const us* qsrc =
        qb + ((size_t)(b * 4096 + q0 + wave * 16 + l15)) * 1024 + h * 128 + hi4 * 8;
#pragma unroll
    for (int m = 0; m < 2; ++m)
#pragma unroll
      for (int ks = 0; ks < 2; ++ks)
        qf[m][ks] = *(const short8*)(qsrc + m * 64 + ks * 32);
  }

  float sumd[2][4];
  f32x4 accO[2][4];
#pragma unroll
  for (int m = 0; m < 2; ++m)
#pragma unroll
    for (int r = 0; r < 4; ++r) {
      sumd[m][r] = 0.f;
      accO[m][r] = (f32x4){0.f, 0.f, 0.f, 0.f};
    }
  float lamh = lam[h];

  const us* kbase0 = kb + (size_t)b * 524288 + kvh * 128;
  const us* vbase0 = vT + ((size_t)(b * 256 + kvh * 64)) * 1024;
  int krow[4], vrow[2];
#pragma unroll
  for (int c = 0; c < 4; ++c) {
    int row = (wave * 4 + c) * 4 + hi4;
    int g = (l15 & 8) | ((l15 & 7) ^ (row & 7));
    krow[c] = row * 512 + g * 8;
  }
#pragma unroll
  for (int c = 0; c < 2; ++c) {
    int row = (wave * 2 + c) * 8 + (lane >> 3);
    int g = (lane & 7) ^ (row & 7);
    vrow[c] = row * 1024 + g * 8;
  }
  int kg0[2], kg1[2], vg[2];
#pragma unroll
  for (int m = 0; m < 2; ++m) {
    kg0[m] = (m * 8 | (hi4 ^ (l15 & 7))) * 8;
    kg1[m] = (m * 8 | ((4 + hi4) ^ (l15 & 7))) * 8;
  }
#pragma unroll
  for (int ks = 0; ks < 2; ++ks) vg[ks] = ((ks * 4 + hi4) ^ (l15 & 7)) * 8;

  auto stage = [&](int buf, int kt2) {
    const us* kk = kbase0 + (size_t)kt2 * 32768;
    const us* vv = vbase0 + kt2 * 64;
#pragma unroll
    for (int c = 0; c < 4; ++c)
      gload16(kk + krow[c], &Klds[buf][(wave * 4 + c) * 512]);
#pragma unroll
    for (int c = 0; c < 2; ++c)
      gload16(vv + vrow[c], &Vlds[buf][(wave * 2 + c) * 512]);
  };

  const float cexp = 0.18033688f;  // 0.125 * log2(e)
  stage(0, 0);
  for (int kt = 0; kt < 16; ++kt) {
    int cur = kt & 1;
    if (kt < 15) {
      stage(cur ^ 1, kt + 1);
      asm volatile("s_waitcnt vmcnt(6)" ::: "memory");
    } else {
      asm volatile("s_waitcnt vmcnt(0)" ::: "memory");
    }
    __builtin_amdgcn_s_barrier();
    __builtin_amdgcn_sched_barrier(0);

    short8 vf[2][4];
#pragma unroll
    for (int ks = 0; ks < 2; ++ks)
#pragma unroll
      for (int nf = 0; nf < 4; ++nf)
        vf[ks][nf] = *(const short8*)&Vlds[cur][(nf * 16 + l15) * 64 + vg[ks]];

#pragma unroll
    for (int m = 0; m < 2; ++m) {
      short8 kf[4][2];
#pragma unroll
      for (int nf = 0; nf < 4; ++nf) {
        kf[nf][0] = *(const short8*)&Klds[cur][(nf * 16 + l15) * 128 + kg0[m]];
        kf[nf][1] = *(const short8*)&Klds[cur][(nf * 16 + l15) * 128 + kg1[m]];
      }
      f32x4 s[4];
      __builtin_amdgcn_s_setprio(1);
#pragma unroll
      for (int nf = 0; nf < 4; ++nf) {
        f32x4 z = (f32x4){0.f, 0.f, 0.f, 0.f};
        z = __builtin_amdgcn_mfma_f32_16x16x32_bf16(qf[m][0], kf[nf][0], z, 0, 0, 0);
        z = __builtin_amdgcn_mfma_f32_16x16x32_bf16(qf[m][1], kf[nf][1], z, 0, 0, 0);
        s[nf] = z;
      }
      __builtin_amdgcn_s_setprio(0);
#pragma unroll
      for (int r = 0; r < 4; ++r) {
        float p0 = fast_exp2(s[0][r] * cexp);
        float p1 = fast_exp2(s[1][r] * cexp);
        float p2 = fast_exp2(s[2][r] * cexp);
        float p3 = fast_exp2(s[3][r] * cexp);
        sumd[m][r] += (p0 + p1) + (p2 + p3);
        unsigned int w0 = cvt_pk_bf16(p0, p1);
        unsigned int w1 = cvt_pk_bf16(p2, p3);
        *(uint2*)&Plds[wave][hi4 * 4 + r][l15 * 4] = make_uint2(w0, w1);
      }
      __builtin_amdgcn_s_setprio(1);
#pragma unroll
      for (int ks = 0; ks < 2; ++ks) {
        short8 pf = *(const short8*)&Plds[wave][l15][ks * 32 + hi4 * 8];
#pragma unroll
        for (int nf = 0; nf < 4; ++nf)
          accO[m][nf] =
              __builtin_amdgcn_mfma_f32_16x16x32_bf16(pf, vf[ks][nf], accO[m][nf], 0, 0, 0);
      }
      __builtin_amdgcn_s_setprio(0);
    }
    asm volatile("s_waitcnt lgkmcnt(0)" ::: "memory");
    __builtin_amdgcn_s_barrier();
    __builtin_amdgcn_sched_barrier(0);
  }

  // epilogue: denom reduce, combine mults, RMSNorm, scale 0.8
#pragma unroll
  for (int m = 0; m < 2; ++m)
#pragma unroll
    for (int r = 0; r < 4; ++r) {
      float sx = sumd[m][r];
      sx += __shfl_xor(sx, 1);
      sx += __shfl_xor(sx, 2);
      sx += __shfl_xor(sx, 4);
      sx += __shfl_xor(sx, 8);
      sumd[m][r] = sx;
    }
#pragma unroll
  for (int r = 0; r < 4; ++r) {
    float inv0 = 1.f / sumd[0][r];
    float inv1 = lamh / sumd[1][r];
    float comb[4];
    float ss = 0.f;
#pragma unroll
    for (int nf = 0; nf < 4; ++nf) {
      comb[nf] = accO[0][nf][r] * inv0 + accO[1][nf][r] * inv1;
      ss += comb[nf] * comb[nf];
    }
    ss += __shfl_xor(ss, 1);
    ss += __shfl_xor(ss, 2);
    ss += __shfl_xor(ss, 4);
    ss += __shfl_xor(ss, 8);
    float sc = rsqrtf(ss * (1.f / 64.f) + 1e-8f) * 0.8f;
    int q = q0 + wave * 16 + hi4 * 4 + r;
    int y = q >> 6, x = q & 63;
    size_t oaddr = ((size_t)b * 4356 + (size_t)(y + 1) * 66 + (x + 1)) * 512 + h * 64;
#pragma unroll
    for (int nf = 0; nf < 4; ++nf) apad[oaddr + nf * 16 + l15] = f2bf(comb[nf] * sc);
  }
}

// ============================================================== launch
extern "C" void kernel_launch(void* const* d_in, const int* in_sizes, int n_in,
                              void* d_out, int out_size, void* d_ws, size_t ws_size,
                              hipStream_t stream) {
  const float* x     = (const float*)d_in[0];
  const float* cross = (const float*)d_in[1];
  const float* wq    = (const float*)d_in[2];
  const float* wk    = (const float*)d_in[3];
  const float* wv    = (const float*)d_in[4];
  const float* wo    = (const float*)d_in[5];
  const float* lq1   = (const float*)d_in[6];
  const float* lq2   = (const float*)d_in[7];
  const float* lk1   = (const float*)d_in[8];
  const float* lk2   = (const float*)d_in[9];
  float* out = (float*)d_out;

  char* ws = (char*)d_ws;
  size_t off = 0;
  auto nxt = [&](size_t bytes) { char* p = ws + off; off += bytes; return p; };
  us* xpadT = (us*)nxt(8921088);   // [2][4356][512] bf16
  us* cpadT = (us*)nxt(2367488);   // [2][1156][512] bf16
  us* apad  = (us*)nxt(8921088);   // [2][4356][512] bf16
  us* wqp = (us*)nxt(9437184);     // [9][1024][512]
  us* wkp = (us*)nxt(4718592);     // [9][512][512]
  us* wvp = (us*)nxt(2359296);     // [9][256][512]
  us* wop = (us*)nxt(4718592);     // [9][512][512]
  us* qb  = (us*)nxt(16777216);    // [2][4096][1024] (rope'd)
  us* kb  = (us*)nxt(2097152);     // [2][1024][512]  (rope'd)
  us* vT  = (us*)nxt(1048576);     // [2][256][1024] (sigma-permuted along k)
  float* lam = (float*)nxt(256);   // [8]
  (void)ws_size; (void)in_sizes; (void)n_in; (void)out_size;

  prep_all<<<4167, 256, 0, stream>>>(x, cross, wq, wk, wv, wo,
                                     lq1, lq2, lk1, lk2,
                                     xpadT, cpadT, apad, wqp, wkp, wvp, wop, lam);
  conv128_fwd<<<512, 256, 0, stream>>>(xpadT, wqp, qb, 1024);
  conv64_all<<<384, 256, 0, stream>>>(cpadT, wkp, wvp, kb, vT);
  attn_kernel<<<dim3(64, 8, 2), 256, 0, stream>>>(qb, kb, vT, lam, apad);
  conv128_out<<<512, 256, 0, stream>>>(apad, wop, out);
}

// Round 15
// 221.323 us; speedup vs baseline: 1.1679x; 1.0062x over previous
//
#include <hip/hip_runtime.h>

// ConvCrossAttention on MI355X (gfx950), bf16 MFMA implementation.
// R15 = R14 + cross-wave phase de-alignment in all conv inner loops:
//       odd-wc waves process ks=1 before ks=0, spreading the post-barrier
//       LDS-read burst against the MFMA burst across waves. Offsets computed
//       inline (no runtime-indexed register arrays). attn/prep unchanged.

typedef __attribute__((ext_vector_type(8))) short short8;
typedef __attribute__((ext_vector_type(4))) float f32x4;
typedef unsigned short us;

__device__ __forceinline__ float bf2f(us u) {
  union { unsigned int i; float f; } v; v.i = ((unsigned int)u) << 16; return v.f;
}
__device__ __forceinline__ us f2bf(float f) {
  union { float f; unsigned int i; } v; v.f = f;
  unsigned int x = v.i;
  return (us)((x + 0x7fffu + ((x >> 16) & 1u)) >> 16);
}

typedef __attribute__((address_space(3))) unsigned int as3_uint;
typedef const __attribute__((address_space(1))) unsigned int as1_uint;
__device__ __forceinline__ void gload16(const us* g, us* l) {
  __builtin_amdgcn_global_load_lds((as1_uint*)g, (as3_uint*)l, 16, 0, 0);
}
__device__ __forceinline__ unsigned int cvt_pk_bf16(float a, float b) {
  unsigned int r;
  asm("v_cvt_pk_bf16_f32 %0, %1, %2" : "=v"(r) : "v"(a), "v"(b));
  return r;
}
__device__ __forceinline__ float fast_exp2(float x) {
  float r;
  asm("v_exp_f32 %0, %1" : "=v"(r) : "v"(x));
  return r;
}
// sin/cos via HW transcendentals (input: revolutions, fract-reduced).
__device__ __forceinline__ void fsincos(float ang, float* sn, float* cs) {
  float r = ang * 0.15915494309f;
  r = r - floorf(r);
  float s, c;
  asm("v_sin_f32 %0, %1" : "=v"(s) : "v"(r));
  asm("v_cos_f32 %0, %1" : "=v"(c) : "v"(r));
  *sn = s; *cs = c;
}

// ================================================= fused prep kernel
__device__ __forceinline__ void transpose_body(
    const float* __restrict__ in, us* __restrict__ outT,
    int b, int y, int ci0, int H, int W, int logW) {
  const int C = 512;
  int padW = W + 2, Ppad = (H + 2) * padW;
  __shared__ float tile[64][65];
  int nt = W * 64;
  for (int idx = threadIdx.x; idx < nt; idx += 256) {
    int ci = idx >> logW, x = idx & (W - 1);
    tile[ci][x] = in[(((size_t)b * C + ci0 + ci) * H + y) * W + x];
  }
  __syncthreads();
  int nt2 = W * 32;
  for (int idx = threadIdx.x; idx < nt2; idx += 256) {
    int px = idx >> 5, c2 = idx & 31;
    unsigned int val = (unsigned int)f2bf(tile[c2 * 2][px]) |
                       ((unsigned int)f2bf(tile[c2 * 2 + 1][px]) << 16);
    *(unsigned int*)(outT + ((size_t)b * Ppad + (size_t)(y + 1) * padW + (px + 1)) * C +
                     ci0 + c2 * 2) = val;
  }
}

__global__ __launch_bounds__(256) void prep_all(
    const float* __restrict__ x, const float* __restrict__ cross,
    const float* __restrict__ wq, const float* __restrict__ wk,
    const float* __restrict__ wv, const float* __restrict__ wo,
    const float* __restrict__ lq1, const float* __restrict__ lq2,
    const float* __restrict__ lk1, const float* __restrict__ lk2,
    us* __restrict__ xpadT, us* __restrict__ cpadT, us* __restrict__ apad,
    us* __restrict__ oq, us* __restrict__ ok, us* __restrict__ ov,
    us* __restrict__ oo, float* __restrict__ lam) {
  int bid = blockIdx.x, tid = threadIdx.x;
  if (bid < 326) {
    int g = bid * 4 + (tid >> 6);
    int t = tid & 63;
    us* base; int W, b, i;
    if (g < 520)      { base = xpadT; W = 64; b = g >= 260; i = g - b * 260; }
    else if (g < 784) { base = cpadT; W = 32; int gg = g - 520; b = gg >= 132; i = gg - b * 132; }
    else              { base = apad; W = 64; int gg = g - 784; b = gg >= 260; i = gg - b * 260; }
    int padW = W + 2, nb = 2 * padW;
    int yy, xx;
    if (i < padW)    { yy = 0; xx = i; }
    else if (i < nb) { yy = W + 1; xx = i - padW; }
    else             { int j = i - nb; yy = 1 + (j >> 1); xx = (j & 1) * (W + 1); }
    size_t p = ((size_t)b * padW * padW + (size_t)yy * padW + xx) * 512 + t * 8;
    *(int4*)(base + p) = make_int4(0, 0, 0, 0);
  } else if (bid < 1350) {
    int i = bid - 326;
    transpose_body(x, xpadT, i >> 9, (i >> 3) & 63, (i & 7) * 64, 64, 64, 6);
  } else if (bid < 1862) {
    int i = bid - 1350;
    transpose_body(cross, cpadT, i >> 8, (i >> 3) & 31, (i & 7) * 64, 32, 32, 5);
  } else if (bid < 4166) {
    int blk = bid - 1862;
    const float* src; us* dst; int Cout, co;
    if (blk < 1024)      { src = wq; dst = oq; Cout = 1024; co = blk; }
    else if (blk < 1536) { src = wk; dst = ok; Cout = 512;  co = blk - 1024; }
    else if (blk < 1792) { src = wv; dst = ov; Cout = 256;  co = blk - 1536; }
    else                 { src = wo; dst = oo; Cout = 512;  co = blk - 1792; }
    __shared__ us l[4608];
    const float* s0 = src + (size_t)co * 4608;
#pragma unroll
    for (int k = 0; k < 18; ++k) { int i = k * 256 + tid; l[i] = f2bf(s0[i]); }
    __syncthreads();
#pragma unroll
    for (int k = 0; k < 9; ++k) {
      int j = k * 256 + tid;
      int t = j >> 8, c2 = j & 255;
      unsigned int val = (unsigned int)l[(c2 * 2) * 9 + t] |
                         ((unsigned int)l[(c2 * 2 + 1) * 9 + t] << 16);
      *(unsigned int*)(dst + (size_t)t * Cout * 512 + (size_t)co * 512 + c2 * 2) = val;
    }
  } else {
    int h = tid >> 5, d = tid & 31;
    float s1 = lq1[h * 64 + d] * lk1[h * 64 + d] +
               lq1[h * 64 + d + 32] * lk1[h * 64 + d + 32];
    float s2 = lq2[h * 64 + d] * lk2[h * 64 + d] +
               lq2[h * 64 + d + 32] * lk2[h * 64 + d + 32];
    for (int m = 16; m; m >>= 1) {
      s1 += __shfl_xor(s1, m);
      s2 += __shfl_xor(s2, m);
    }
    if (d == 0) lam[h] = -(expf(s1) - expf(s2) + 0.2f);
  }
}

// ================================================= Q conv: 128x128 tile, dbuf, rope'd epilogue
__global__ __launch_bounds__(256) void conv128_fwd(
    const us* __restrict__ inT, const us* __restrict__ wp,
    us* __restrict__ out, int Cout) {
  __shared__ __align__(16) us sh[2][2][128][64];   // 64 KB
  int bid = blockIdx.x;                       // 512 blocks
  int v = (bid & 7) * 64 + (bid >> 3);        // chunked XCD swizzle
  int pxt = v & 31, cot = (v >> 5) & 7, b = v >> 8;
  int p0 = pxt * 128, co0 = cot * 128;
  int tid = threadIdx.x;
  int wave = tid >> 6, lane = tid & 63, l15 = lane & 15, hi4 = lane >> 4;
  int wr = wave >> 1, wc = wave & 1;
  f32x4 acc[4][4];
#pragma unroll
  for (int m = 0; m < 4; ++m)
#pragma unroll
    for (int n = 0; n < 4; ++n) acc[m][n] = (f32x4){0.f, 0.f, 0.f, 0.f};

  int arow[4], brow[4];
#pragma unroll
  for (int c = 0; c < 4; ++c) {
    int row = c * 32 + (tid >> 3);
    int g = (tid & 7) ^ (row & 7);
    int px = p0 + row;
    int y = px >> 6, x = px & 63;
    arow[c] = (y * 66 + x) * 512 + g * 8;
    brow[c] = (co0 + row) * 512 + g * 8;
  }
  int rowA[4], rowB[4];
#pragma unroll
  for (int m = 0; m < 4; ++m) {
    rowA[m] = (wr * 64 + m * 16 + l15) * 64;
    rowB[m] = (wc * 64 + m * 16 + l15) * 64;
  }
  const us* abase = inT + (size_t)b * 66 * 66 * 512;

  auto stage = [&](int buf, int t, int ci) {
    int ky = (t * 11) >> 5, kx = t - ky * 3;
    const us* as = abase + (ky * 66 + kx) * 512 + ci;
    const us* bs = wp + (size_t)t * Cout * 512 + ci;
    us* la = &sh[buf][0][0][0];
    us* lb = &sh[buf][1][0][0];
#pragma unroll
    for (int c = 0; c < 4; ++c) {
      gload16(as + arow[c], la + c * 2048 + wave * 512);
      gload16(bs + brow[c], lb + c * 2048 + wave * 512);
    }
  };

  stage(0, 0, 0);
  __syncthreads();
  for (int cc = 0; cc < 8; ++cc) {
#pragma unroll
    for (int t = 0; t < 9; ++t) {
      int s = cc * 9 + t;
      int cur = s & 1;
      if (s < 71) {
        int tn = (t == 8) ? 0 : t + 1;
        int cn = (t == 8) ? (cc + 1) << 6 : cc << 6;
        stage(cur ^ 1, tn, cn);
      }
      const us* la = &sh[cur][0][0][0];
      const us* lb = &sh[cur][1][0][0];
#pragma unroll
      for (int ksi = 0; ksi < 2; ++ksi) {
        int ks = ksi ^ wc;                               // phase de-alignment
        int gb = ((ks * 4 + hi4) ^ (l15 & 7)) * 8;       // inline, no array idx
        short8 af[4], bf[4];
#pragma unroll
        for (int m = 0; m < 4; ++m) af[m] = *(const short8*)(la + rowA[m] + gb);
#pragma unroll
        for (int n = 0; n < 4; ++n) bf[n] = *(const short8*)(lb + rowB[n] + gb);
#pragma unroll
        for (int m = 0; m < 4; ++m)
#pragma unroll
          for (int n = 0; n < 4; ++n)
            acc[m][n] = __builtin_amdgcn_mfma_f32_16x16x32_bf16(af[m], bf[n], acc[m][n], 0, 0, 0);
      }
      __syncthreads();
    }
  }
  // RoPE epilogue: pairs (2j,2j+1) along co sit in adjacent lanes
  int par = lane & 1;
#pragma unroll
  for (int n = 0; n < 4; ++n) {
    int co = co0 + wc * 64 + n * 16 + l15;
    int j = (co & 127) >> 1;
    float th = exp2f(-(float)j * 0.20762050593f);  // 10000^(-j/64)
    float sth, cth;
    fsincos(th, &sth, &cth);
#pragma unroll
    for (int m = 0; m < 4; ++m) {
      int pxb = p0 + wr * 64 + m * 16 + hi4 * 4;
      float s0, c0;
      fsincos((float)pxb * th, &s0, &c0);
#pragma unroll
      for (int r = 0; r < 4; ++r) {
        float xv = acc[m][n][r];
        float ov = __shfl_xor(xv, 1);
        float y = par ? fmaf(ov, s0, xv * c0) : fmaf(xv, c0, -ov * s0);
        out[((size_t)b * 4096 + (pxb + r)) * Cout + co] = f2bf(y);
        float c1 = c0 * cth - s0 * sth;       // rotate angle by th (px+1)
        s0 = fmaf(c0, sth, s0 * cth);
        c0 = c1;
      }
    }
  }
}

// ================================================= 64^2 conv body (K,V), 32KB LDS
template <int TRANS_OUT, int ROPE>
__device__ __forceinline__ void conv64_body(
    const us* __restrict__ inT, const us* __restrict__ wp,
    us* __restrict__ out, int Cout, int logCoT, int bid, int ngrid, us* sh) {
  int nchunk = ngrid >> 3;
  int v = (bid & 7) * nchunk + (bid >> 3);
  int yt = v & 15;
  int cot = (v >> 4) & ((1 << logCoT) - 1);
  int b = v >> (4 + logCoT);
  int p0 = yt * 64, co0 = cot * 64;
  const int W = 32, logW = 5, padW = 34, HW = 1024;
  int tid = threadIdx.x;
  int wave = tid >> 6, lane = tid & 63, l15 = lane & 15, hi4 = lane >> 4;
  f32x4 acc[4];
#pragma unroll
  for (int i = 0; i < 4; ++i) acc[i] = (f32x4){0.f, 0.f, 0.f, 0.f};

  int arow[2], brow[2];
#pragma unroll
  for (int c = 0; c < 2; ++c) {
    int row = (wave * 2 + c) * 8 + (lane >> 3);
    int g = (lane & 7) ^ (row & 7);
    int px = p0 + row;
    int y = px >> logW, x = px & (W - 1);
    arow[c] = (y * padW + x) * 512 + g * 8;
    brow[c] = (co0 + row) * 512 + g * 8;
  }
  int rowA[4], rowB0 = (16 * wave + l15) * 64;
#pragma unroll
  for (int i = 0; i < 4; ++i) rowA[i] = (i * 16 + l15) * 64;

  const us* abase = inT + (size_t)b * padW * padW * 512;

  auto stage = [&](int buf, int t, int ci) {
    int ky = (t * 11) >> 5, kx = t - ky * 3;
    const us* as = abase + (ky * padW + kx) * 512 + ci;
    const us* bs = wp + (size_t)t * Cout * 512 + ci;
    us* la = sh + buf * 8192;
    us* lb = la + 4096;
#pragma unroll
    for (int c = 0; c < 2; ++c) {
      gload16(as + arow[c], la + (wave * 2 + c) * 512);
      gload16(bs + brow[c], lb + (wave * 2 + c) * 512);
    }
  };

  stage(0, 0, 0);
  __syncthreads();
  for (int cc = 0; cc < 8; ++cc) {
#pragma unroll
    for (int t = 0; t < 9; ++t) {
      int s = cc * 9 + t;
      int cur = s & 1;
      if (s < 71) {
        int tn = (t == 8) ? 0 : t + 1;
        int cn = (t == 8) ? (cc + 1) << 6 : cc << 6;
        stage(cur ^ 1, tn, cn);
      }
      const us* la = sh + cur * 8192;
      const us* lb = la + 4096;
#pragma unroll
      for (int ksi = 0; ksi < 2; ++ksi) {
        int ks = ksi ^ (wave & 1);                       // phase de-alignment
        int gb = ((ks * 4 + hi4) ^ (l15 & 7)) * 8;
        short8 bf = *(const short8*)(lb + rowB0 + gb);
#pragma unroll
        for (int i = 0; i < 4; ++i) {
          short8 af = *(const short8*)(la + rowA[i] + gb);
          acc[i] = __builtin_amdgcn_mfma_f32_16x16x32_bf16(af, bf, acc[i], 0, 0, 0);
        }
      }
      __syncthreads();
    }
  }
  if (ROPE) {
    int co = co0 + 16 * wave + l15;
    int j = (co & 127) >> 1;
    float th = exp2f(-(float)j * 0.20762050593f);
    float sth, cth;
    fsincos(th, &sth, &cth);
    int par = lane & 1;
#pragma unroll
    for (int i = 0; i < 4; ++i) {
      int pxb = p0 + i * 16 + hi4 * 4;
      float s0, c0;
      fsincos((float)pxb * th, &s0, &c0);
#pragma unroll
      for (int r = 0; r < 4; ++r) {
        float xv = acc[i][r];
        float ov = __shfl_xor(xv, 1);
        float y = par ? fmaf(ov, s0, xv * c0) : fmaf(xv, c0, -ov * s0);
        out[((size_t)b * HW + (pxb + r)) * Cout + co] = f2bf(y);
        float c1 = c0 * cth - s0 * sth;
        s0 = fmaf(c0, sth, s0 * cth);
        c0 = c1;
      }
    }
  } else {
#pragma unroll
    for (int i = 0; i < 4; ++i)
#pragma unroll
      for (int r = 0; r < 4; ++r) {
        int px = TRANS_OUT ? (p0 + (hi4 * 4 + r) * 4 + i)  // sigma(k)=(k%16)*4+k/16
                           : (p0 + i * 16 + hi4 * 4 + r);
        int co = co0 + 16 * wave + l15;
        us val = f2bf(acc[i][r]);
        if (TRANS_OUT)
          out[((size_t)b * Cout + co) * HW + px] = val;
        else
          out[((size_t)b * HW + px) * Cout + co] = val;
      }
  }
}

__global__ __launch_bounds__(256) void conv64_all(
    const us* __restrict__ cpadT, const us* __restrict__ wkp,
    const us* __restrict__ wvp, us* __restrict__ kb, us* __restrict__ vT) {
  __shared__ __align__(16) us sh[2][2][64][64];  // 32 KB
  int bid = blockIdx.x;
  if (bid < 256) conv64_body<0, 1>(cpadT, wkp, kb, 512, 3, bid, 256, &sh[0][0][0][0]);
  else           conv64_body<1, 0>(cpadT, wvp, vT, 256, 2, bid - 256, 128, &sh[0][0][0][0]);
}

// ================================================= final conv: 128co x 64px tile, grid 512
__global__ __launch_bounds__(256) void conv128_out(
    const us* __restrict__ apad, const us* __restrict__ wp,
    float* __restrict__ out) {
  __shared__ __align__(16) us lds[2][12288];   // [buf][A 128x64 | B 64x64]
  int bid = blockIdx.x;                        // 512 blocks
  int v = (bid & 7) * 64 + (bid >> 3);         // chunked XCD swizzle
  int pxt = v & 63, cot = (v >> 6) & 3, b = v >> 8;
  int p0 = pxt * 64, co0 = cot * 128;
  int tid = threadIdx.x;
  int wave = tid >> 6, lane = tid & 63, l15 = lane & 15, hi4 = lane >> 4;
  int wr = wave >> 1, wc = wave & 1;
  f32x4 acc[4][2];
#pragma unroll
  for (int m = 0; m < 4; ++m)
#pragma unroll
    for (int n = 0; n < 2; ++n) acc[m][n] = (f32x4){0.f, 0.f, 0.f, 0.f};

  int arow[4], brow[2];
#pragma unroll
  for (int c = 0; c < 4; ++c) {
    int row = c * 32 + (tid >> 3);
    int g = (tid & 7) ^ (row & 7);
    arow[c] = (co0 + row) * 512 + g * 8;       // weight rows (co)
  }
#pragma unroll
  for (int c = 0; c < 2; ++c) {
    int row = c * 32 + (tid >> 3);
    int g = (tid & 7) ^ (row & 7);
    int px = p0 + row;
    int y = px >> 6, x = px & 63;
    brow[c] = (y * 66 + x) * 512 + g * 8;      // pixel rows
  }
  int rowA[4], rowB[2];
#pragma unroll
  for (int m = 0; m < 4; ++m) rowA[m] = (wr * 64 + m * 16 + l15) * 64;
#pragma unroll
  for (int n = 0; n < 2; ++n) rowB[n] = (wc * 32 + n * 16 + l15) * 64;
  const us* bbase = apad + (size_t)b * 4356 * 512;

  auto stage = [&](int buf, int t, int ci) {
    int ky = (t * 11) >> 5, kx = t - ky * 3;
    const us* as = wp + (size_t)t * 512 * 512 + ci;
    const us* bs = bbase + (ky * 66 + kx) * 512 + ci;
    us* la = &lds[buf][0];
    us* lb = la + 8192;
#pragma unroll
    for (int c = 0; c < 4; ++c)
      gload16(as + arow[c], la + c * 2048 + wave * 512);
#pragma unroll
    for (int c = 0; c < 2; ++c)
      gload16(bs + brow[c], lb + c * 2048 + wave * 512);
  };

  stage(0, 0, 0);
  __syncthreads();
  for (int cc = 0; cc < 8; ++cc) {
#pragma unroll
    for (int t = 0; t < 9; ++t) {
      int s = cc * 9 + t;
      int cur = s & 1;
      if (s < 71) {
        int tn = (t == 8) ? 0 : t + 1;
        int cn = (t == 8) ? (cc + 1) << 6 : cc << 6;
        stage(cur ^ 1, tn, cn);
      }
      const us* la = &lds[cur][0];
      const us* lb = la + 8192;
#pragma unroll
      for (int ksi = 0; ksi < 2; ++ksi) {
        int ks = ksi ^ wc;                               // phase de-alignment
        int gb = ((ks * 4 + hi4) ^ (l15 & 7)) * 8;
        short8 af[4], bf[2];
#pragma unroll
        for (int m = 0; m < 4; ++m) af[m] = *(const short8*)(la + rowA[m] + gb);
#pragma unroll
        for (int n = 0; n < 2; ++n) bf[n] = *(const short8*)(lb + rowB[n] + gb);
#pragma unroll
        for (int m = 0; m < 4; ++m)
#pragma unroll
          for (int n = 0; n < 2; ++n)
            acc[m][n] = __builtin_amdgcn_mfma_f32_16x16x32_bf16(af[m], bf[n], acc[m][n], 0, 0, 0);
      }
      __syncthreads();
    }
  }
#pragma unroll
  for (int m = 0; m < 4; ++m)
#pragma unroll
    for (int n = 0; n < 2; ++n)
#pragma unroll
      for (int r = 0; r < 4; ++r) {
        int co = co0 + wr * 64 + m * 16 + hi4 * 4 + r;
        int px = p0 + wc * 32 + n * 16 + l15;
        out[((size_t)b * 512 + co) * 4096 + px] = acc[m][n][r];
      }
}

// ================================================= differential GQA attention + RMSNorm
// QBLK=64 (grid 1024); R7 sync structure (vmcnt(6), 2 barriers). Unchanged.
__global__ __launch_bounds__(256) void attn_kernel(
    const us* __restrict__ qb, const us* __restrict__ kb,
    const us* __restrict__ vT, const float* __restrict__ lam,
    us* __restrict__ apad) {
  int qt = blockIdx.x, h = blockIdx.y, b = blockIdx.z;
  int kvh = h >> 1;
  int tid = threadIdx.x;
  int wave = tid >> 6, lane = tid & 63, l15 = lane & 15, hi4 = lane >> 4;
  __shared__ __align__(16) us Klds[2][8192];   // [buf][64 k rows][128 d]
  __shared__ __align__(16) us Vlds[2][4096];   // [buf][64 dv rows][64 k']
  __shared__ __align__(16) us Plds[4][16][72];

  int q0 = qt * 64;
  short8 qf[2][2];  // [m][ks]
  {
    const us* qsrc =
        qb + ((size_t)(b * 4096 + q0 + wave * 16 + l15)) * 1024 + h * 128 + hi4 * 8;
#pragma unroll
    for (int m = 0; m < 2; ++m)
#pragma unroll
      for (int ks = 0; ks < 2; ++ks)
        qf[m][ks] = *(const short8*)(qsrc + m * 64 + ks * 32);
  }

  float sumd[2][4];
  f32x4 accO[2][4];
#pragma unroll
  for (int m = 0; m < 2; ++m)
#pragma unroll
    for (int r = 0; r < 4; ++r) {
      sumd[m][r] = 0.f;
      accO[m][r] = (f32x4){0.f, 0.f, 0.f, 0.f};
    }
  float lamh = lam[h];

  const us* kbase0 = kb + (size_t)b * 524288 + kvh * 128;
  const us* vbase0 = vT + ((size_t)(b * 256 + kvh * 64)) * 1024;
  int krow[4], vrow[2];
#pragma unroll
  for (int c = 0; c < 4; ++c) {
    int row = (wave * 4 + c) * 4 + hi4;
    int g = (l15 & 8) | ((l15 & 7) ^ (row & 7));
    krow[c] = row * 512 + g * 8;
  }
#pragma unroll
  for (int c = 0; c < 2; ++c) {
    int row = (wave * 2 + c) * 8 + (lane >> 3);
    int g = (lane & 7) ^ (row & 7);
    vrow[c] = row * 1024 + g * 8;
  }
  int kg0[2], kg1[2], vg[2];
#pragma unroll
  for (int m = 0; m < 2; ++m) {
    kg0[m] = (m * 8 | (hi4 ^ (l15 & 7))) * 8;
    kg1[m] = (m * 8 | ((4 + hi4) ^ (l15 & 7))) * 8;
  }
#pragma unroll
  for (int ks = 0; ks < 2; ++ks) vg[ks] = ((ks * 4 + hi4) ^ (l15 & 7)) * 8;

  auto stage = [&](int buf, int kt2) {
    const us* kk = kbase0 + (size_t)kt2 * 32768;
    const us* vv = vbase0 + kt2 * 64;
#pragma unroll
    for (int c = 0; c < 4; ++c)
      gload16(kk + krow[c], &Klds[buf][(wave * 4 + c) * 512]);
#pragma unroll
    for (int c = 0; c < 2; ++c)
      gload16(vv + vrow[c], &Vlds[buf][(wave * 2 + c) * 512]);
  };

  const float cexp = 0.18033688f;  // 0.125 * log2(e)
  stage(0, 0);
  for (int kt = 0; kt < 16; ++kt) {
    int cur = kt & 1;
    if (kt < 15) {
      stage(cur ^ 1, kt + 1);
      asm volatile("s_waitcnt vmcnt(6)" ::: "memory");
    } else {
      asm volatile("s_waitcnt vmcnt(0)" ::: "memory");
    }
    __builtin_amdgcn_s_barrier();
    __builtin_amdgcn_sched_barrier(0);

    short8 vf[2][4];
#pragma unroll
    for (int ks = 0; ks < 2; ++ks)
#pragma unroll
      for (int nf = 0; nf < 4; ++nf)
        vf[ks][nf] = *(const short8*)&Vlds[cur][(nf * 16 + l15) * 64 + vg[ks]];

#pragma unroll
    for (int m = 0; m < 2; ++m) {
      short8 kf[4][2];
#pragma unroll
      for (int nf = 0; nf < 4; ++nf) {
        kf[nf][0] = *(const short8*)&Klds[cur][(nf * 16 + l15) * 128 + kg0[m]];
        kf[nf][1] = *(const short8*)&Klds[cur][(nf * 16 + l15) * 128 + kg1[m]];
      }
      f32x4 s[4];
      __builtin_amdgcn_s_setprio(1);
#pragma unroll
      for (int nf = 0; nf < 4; ++nf) {
        f32x4 z = (f32x4){0.f, 0.f, 0.f, 0.f};
        z = __builtin_amdgcn_mfma_f32_16x16x32_bf16(qf[m][0], kf[nf][0], z, 0, 0, 0);
        z = __builtin_amdgcn_mfma_f32_16x16x32_bf16(qf[m][1], kf[nf][1], z, 0, 0, 0);
        s[nf] = z;
      }
      __builtin_amdgcn_s_setprio(0);
#pragma unroll
      for (int r = 0; r < 4; ++r) {
        float p0 = fast_exp2(s[0][r] * cexp);
        float p1 = fast_exp2(s[1][r] * cexp);
        float p2 = fast_exp2(s[2][r] * cexp);
        float p3 = fast_exp2(s[3][r] * cexp);
        sumd[m][r] += (p0 + p1) + (p2 + p3);
        unsigned int w0 = cvt_pk_bf16(p0, p1);
        unsigned int w1 = cvt_pk_bf16(p2, p3);
        *(uint2*)&Plds[wave][hi4 * 4 + r][l15 * 4] = make_uint2(w0, w1);
      }
      __builtin_amdgcn_s_setprio(1);
#pragma unroll
      for (int ks = 0; ks < 2; ++ks) {
        short8 pf = *(const short8*)&Plds[wave][l15][ks * 32 + hi4 * 8];
#pragma unroll
        for (int nf = 0; nf < 4; ++nf)
          accO[m][nf] =
              __builtin_amdgcn_mfma_f32_16x16x32_bf16(pf, vf[ks][nf], accO[m][nf], 0, 0, 0);
      }
      __builtin_amdgcn_s_setprio(0);
    }
    asm volatile("s_waitcnt lgkmcnt(0)" ::: "memory");
    __builtin_amdgcn_s_barrier();
    __builtin_amdgcn_sched_barrier(0);
  }

  // epilogue: denom reduce, combine mults, RMSNorm, scale 0.8
#pragma unroll
  for (int m = 0; m < 2; ++m)
#pragma unroll
    for (int r = 0; r < 4; ++r) {
      float sx = sumd[m][r];
      sx += __shfl_xor(sx, 1);
      sx += __shfl_xor(sx, 2);
      sx += __shfl_xor(sx, 4);
      sx += __shfl_xor(sx, 8);
      sumd[m][r] = sx;
    }
#pragma unroll
  for (int r = 0; r < 4; ++r) {
    float inv0 = 1.f / sumd[0][r];
    float inv1 = lamh / sumd[1][r];
    float comb[4];
    float ss = 0.f;
#pragma unroll
    for (int nf = 0; nf < 4; ++nf) {
      comb[nf] = accO[0][nf][r] * inv0 + accO[1][nf][r] * inv1;
      ss += comb[nf] * comb[nf];
    }
    ss += __shfl_xor(ss, 1);
    ss += __shfl_xor(ss, 2);
    ss += __shfl_xor(ss, 4);
    ss += __shfl_xor(ss, 8);
    float sc = rsqrtf(ss * (1.f / 64.f) + 1e-8f) * 0.8f;
    int q = q0 + wave * 16 + hi4 * 4 + r;
    int y = q >> 6, x = q & 63;
    size_t oaddr = ((size_t)b * 4356 + (size_t)(y + 1) * 66 + (x + 1)) * 512 + h * 64;
#pragma unroll
    for (int nf = 0; nf < 4; ++nf) apad[oaddr + nf * 16 + l15] = f2bf(comb[nf] * sc);
  }
}

// ============================================================== launch
extern "C" void kernel_launch(void* const* d_in, const int* in_sizes, int n_in,
                              void* d_out, int out_size, void* d_ws, size_t ws_size,
                              hipStream_t stream) {
  const float* x     = (const float*)d_in[0];
  const float* cross = (const float*)d_in[1];
  const float* wq    = (const float*)d_in[2];
  const float* wk    = (const float*)d_in[3];
  const float* wv    = (const float*)d_in[4];
  const float* wo    = (const float*)d_in[5];
  const float* lq1   = (const float*)d_in[6];
  const float* lq2   = (const float*)d_in[7];
  const float* lk1   = (const float*)d_in[8];
  const float* lk2   = (const float*)d_in[9];
  float* out = (float*)d_out;

  char* ws = (char*)d_ws;
  size_t off = 0;
  auto nxt = [&](size_t bytes) { char* p = ws + off; off += bytes; return p; };
  us* xpadT = (us*)nxt(8921088);   // [2][4356][512] bf16
  us* cpadT = (us*)nxt(2367488);   // [2][1156][512] bf16
  us* apad  = (us*)nxt(8921088);   // [2][4356][512] bf16
  us* wqp = (us*)nxt(9437184);     // [9][1024][512]
  us* wkp = (us*)nxt(4718592);     // [9][512][512]
  us* wvp = (us*)nxt(2359296);     // [9][256][512]
  us* wop = (us*)nxt(4718592);     // [9][512][512]
  us* qb  = (us*)nxt(16777216);    // [2][4096][1024] (rope'd)
  us* kb  = (us*)nxt(2097152);     // [2][1024][512]  (rope'd)
  us* vT  = (us*)nxt(1048576);     // [2][256][1024] (sigma-permuted along k)
  float* lam = (float*)nxt(256);   // [8]
  (void)ws_size; (void)in_sizes; (void)n_in; (void)out_size;

  prep_all<<<4167, 256, 0, stream>>>(x, cross, wq, wk, wv, wo,
                                     lq1, lq2, lk1, lk2,
                                     xpadT, cpadT, apad, wqp, wkp, wvp, wop, lam);
  conv128_fwd<<<512, 256, 0, stream>>>(xpadT, wqp, qb, 1024);
  conv64_all<<<384, 256, 0, stream>>>(cpadT, wkp, wvp, kb, vT);
  attn_kernel<<<dim3(64, 8, 2), 256, 0, stream>>>(qb, kb, vT, lam, apad);
  conv128_out<<<512, 256, 0, stream>>>(apad, wop, out);
}

// Round 16
// 220.469 us; speedup vs baseline: 1.1724x; 1.0039x over previous
//
#include <hip/hip_runtime.h>

// ConvCrossAttention on MI355X (gfx950), bf16 MFMA implementation.
// R16 = R15 + prep_all vectorization: float4 input reads in transpose and
//       weight-pack branches (4B/lane -> 16B/lane; prep was at 55% of HBM BW).
//       Everything else unchanged.

typedef __attribute__((ext_vector_type(8))) short short8;
typedef __attribute__((ext_vector_type(4))) float f32x4;
typedef unsigned short us;

__device__ __forceinline__ float bf2f(us u) {
  union { unsigned int i; float f; } v; v.i = ((unsigned int)u) << 16; return v.f;
}
__device__ __forceinline__ us f2bf(float f) {
  union { float f; unsigned int i; } v; v.f = f;
  unsigned int x = v.i;
  return (us)((x + 0x7fffu + ((x >> 16) & 1u)) >> 16);
}

typedef __attribute__((address_space(3))) unsigned int as3_uint;
typedef const __attribute__((address_space(1))) unsigned int as1_uint;
__device__ __forceinline__ void gload16(const us* g, us* l) {
  __builtin_amdgcn_global_load_lds((as1_uint*)g, (as3_uint*)l, 16, 0, 0);
}
__device__ __forceinline__ unsigned int cvt_pk_bf16(float a, float b) {
  unsigned int r;
  asm("v_cvt_pk_bf16_f32 %0, %1, %2" : "=v"(r) : "v"(a), "v"(b));
  return r;
}
__device__ __forceinline__ float fast_exp2(float x) {
  float r;
  asm("v_exp_f32 %0, %1" : "=v"(r) : "v"(x));
  return r;
}
// sin/cos via HW transcendentals (input: revolutions, fract-reduced).
__device__ __forceinline__ void fsincos(float ang, float* sn, float* cs) {
  float r = ang * 0.15915494309f;
  r = r - floorf(r);
  float s, c;
  asm("v_sin_f32 %0, %1" : "=v"(s) : "v"(r));
  asm("v_cos_f32 %0, %1" : "=v"(c) : "v"(r));
  *sn = s; *cs = c;
}

// ================================================= fused prep kernel
__device__ __forceinline__ void transpose_body(
    const float* __restrict__ in, us* __restrict__ outT,
    int b, int y, int ci0, int H, int W, int logW) {
  const int C = 512;
  int padW = W + 2, Ppad = (H + 2) * padW;
  __shared__ float tile[64][65];
  int logW4 = logW - 2;
  int nt4 = (W >> 2) * 64;
  for (int idx = threadIdx.x; idx < nt4; idx += 256) {
    int ci = idx >> logW4, x4 = idx & ((W >> 2) - 1);
    float4 v = *(const float4*)(in + (((size_t)b * C + ci0 + ci) * H + y) * W + x4 * 4);
    tile[ci][x4 * 4 + 0] = v.x;
    tile[ci][x4 * 4 + 1] = v.y;
    tile[ci][x4 * 4 + 2] = v.z;
    tile[ci][x4 * 4 + 3] = v.w;
  }
  __syncthreads();
  int nt2 = W * 32;
  for (int idx = threadIdx.x; idx < nt2; idx += 256) {
    int px = idx >> 5, c2 = idx & 31;
    unsigned int val = (unsigned int)f2bf(tile[c2 * 2][px]) |
                       ((unsigned int)f2bf(tile[c2 * 2 + 1][px]) << 16);
    *(unsigned int*)(outT + ((size_t)b * Ppad + (size_t)(y + 1) * padW + (px + 1)) * C +
                     ci0 + c2 * 2) = val;
  }
}

__global__ __launch_bounds__(256) void prep_all(
    const float* __restrict__ x, const float* __restrict__ cross,
    const float* __restrict__ wq, const float* __restrict__ wk,
    const float* __restrict__ wv, const float* __restrict__ wo,
    const float* __restrict__ lq1, const float* __restrict__ lq2,
    const float* __restrict__ lk1, const float* __restrict__ lk2,
    us* __restrict__ xpadT, us* __restrict__ cpadT, us* __restrict__ apad,
    us* __restrict__ oq, us* __restrict__ ok, us* __restrict__ ov,
    us* __restrict__ oo, float* __restrict__ lam) {
  int bid = blockIdx.x, tid = threadIdx.x;
  if (bid < 326) {
    int g = bid * 4 + (tid >> 6);
    int t = tid & 63;
    us* base; int W, b, i;
    if (g < 520)      { base = xpadT; W = 64; b = g >= 260; i = g - b * 260; }
    else if (g < 784) { base = cpadT; W = 32; int gg = g - 520; b = gg >= 132; i = gg - b * 132; }
    else              { base = apad; W = 64; int gg = g - 784; b = gg >= 260; i = gg - b * 260; }
    int padW = W + 2, nb = 2 * padW;
    int yy, xx;
    if (i < padW)    { yy = 0; xx = i; }
    else if (i < nb) { yy = W + 1; xx = i - padW; }
    else             { int j = i - nb; yy = 1 + (j >> 1); xx = (j & 1) * (W + 1); }
    size_t p = ((size_t)b * padW * padW + (size_t)yy * padW + xx) * 512 + t * 8;
    *(int4*)(base + p) = make_int4(0, 0, 0, 0);
  } else if (bid < 1350) {
    int i = bid - 326;
    transpose_body(x, xpadT, i >> 9, (i >> 3) & 63, (i & 7) * 64, 64, 64, 6);
  } else if (bid < 1862) {
    int i = bid - 1350;
    transpose_body(cross, cpadT, i >> 8, (i >> 3) & 31, (i & 7) * 64, 32, 32, 5);
  } else if (bid < 4166) {
    int blk = bid - 1862;
    const float* src; us* dst; int Cout, co;
    if (blk < 1024)      { src = wq; dst = oq; Cout = 1024; co = blk; }
    else if (blk < 1536) { src = wk; dst = ok; Cout = 512;  co = blk - 1024; }
    else if (blk < 1792) { src = wv; dst = ov; Cout = 256;  co = blk - 1536; }
    else                 { src = wo; dst = oo; Cout = 512;  co = blk - 1792; }
    __shared__ us l[4608];
    const float* s0 = src + (size_t)co * 4608;
#pragma unroll
    for (int k = 0; k < 5; ++k) {
      int idx = k * 256 + tid;
      if (idx < 1152) {
        float4 v = *(const float4*)(s0 + idx * 4);
        l[idx * 4 + 0] = f2bf(v.x);
        l[idx * 4 + 1] = f2bf(v.y);
        l[idx * 4 + 2] = f2bf(v.z);
        l[idx * 4 + 3] = f2bf(v.w);
      }
    }
    __syncthreads();
#pragma unroll
    for (int k = 0; k < 9; ++k) {
      int j = k * 256 + tid;
      int t = j >> 8, c2 = j & 255;
      unsigned int val = (unsigned int)l[(c2 * 2) * 9 + t] |
                         ((unsigned int)l[(c2 * 2 + 1) * 9 + t] << 16);
      *(unsigned int*)(dst + (size_t)t * Cout * 512 + (size_t)co * 512 + c2 * 2) = val;
    }
  } else {
    int h = tid >> 5, d = tid & 31;
    float s1 = lq1[h * 64 + d] * lk1[h * 64 + d] +
               lq1[h * 64 + d + 32] * lk1[h * 64 + d + 32];
    float s2 = lq2[h * 64 + d] * lk2[h * 64 + d] +
               lq2[h * 64 + d + 32] * lk2[h * 64 + d + 32];
    for (int m = 16; m; m >>= 1) {
      s1 += __shfl_xor(s1, m);
      s2 += __shfl_xor(s2, m);
    }
    if (d == 0) lam[h] = -(expf(s1) - expf(s2) + 0.2f);
  }
}

// ================================================= Q conv: 128x128 tile, dbuf, rope'd epilogue
__global__ __launch_bounds__(256) void conv128_fwd(
    const us* __restrict__ inT, const us* __restrict__ wp,
    us* __restrict__ out, int Cout) {
  __shared__ __align__(16) us sh[2][2][128][64];   // 64 KB
  int bid = blockIdx.x;                       // 512 blocks
  int v = (bid & 7) * 64 + (bid >> 3);        // chunked XCD swizzle
  int pxt = v & 31, cot = (v >> 5) & 7, b = v >> 8;
  int p0 = pxt * 128, co0 = cot * 128;
  int tid = threadIdx.x;
  int wave = tid >> 6, lane = tid & 63, l15 = lane & 15, hi4 = lane >> 4;
  int wr = wave >> 1, wc = wave & 1;
  f32x4 acc[4][4];
#pragma unroll
  for (int m = 0; m < 4; ++m)
#pragma unroll
    for (int n = 0; n < 4; ++n) acc[m][n] = (f32x4){0.f, 0.f, 0.f, 0.f};

  int arow[4], brow[4];
#pragma unroll
  for (int c = 0; c < 4; ++c) {
    int row = c * 32 + (tid >> 3);
    int g = (tid & 7) ^ (row & 7);
    int px = p0 + row;
    int y = px >> 6, x = px & 63;
    arow[c] = (y * 66 + x) * 512 + g * 8;
    brow[c] = (co0 + row) * 512 + g * 8;
  }
  int rowA[4], rowB[4];
#pragma unroll
  for (int m = 0; m < 4; ++m) {
    rowA[m] = (wr * 64 + m * 16 + l15) * 64;
    rowB[m] = (wc * 64 + m * 16 + l15) * 64;
  }
  const us* abase = inT + (size_t)b * 66 * 66 * 512;

  auto stage = [&](int buf, int t, int ci) {
    int ky = (t * 11) >> 5, kx = t - ky * 3;
    const us* as = abase + (ky * 66 + kx) * 512 + ci;
    const us* bs = wp + (size_t)t * Cout * 512 + ci;
    us* la = &sh[buf][0][0][0];
    us* lb = &sh[buf][1][0][0];
#pragma unroll
    for (int c = 0; c < 4; ++c) {
      gload16(as + arow[c], la + c * 2048 + wave * 512);
      gload16(bs + brow[c], lb + c * 2048 + wave * 512);
    }
  };

  stage(0, 0, 0);
  __syncthreads();
  for (int cc = 0; cc < 8; ++cc) {
#pragma unroll
    for (int t = 0; t < 9; ++t) {
      int s = cc * 9 + t;
      int cur = s & 1;
      if (s < 71) {
        int tn = (t == 8) ? 0 : t + 1;
        int cn = (t == 8) ? (cc + 1) << 6 : cc << 6;
        stage(cur ^ 1, tn, cn);
      }
      const us* la = &sh[cur][0][0][0];
      const us* lb = &sh[cur][1][0][0];
#pragma unroll
      for (int ksi = 0; ksi < 2; ++ksi) {
        int ks = ksi ^ wc;                               // phase de-alignment
        int gb = ((ks * 4 + hi4) ^ (l15 & 7)) * 8;       // inline, no array idx
        short8 af[4], bf[4];
#pragma unroll
        for (int m = 0; m < 4; ++m) af[m] = *(const short8*)(la + rowA[m] + gb);
#pragma unroll
        for (int n = 0; n < 4; ++n) bf[n] = *(const short8*)(lb + rowB[n] + gb);
#pragma unroll
        for (int m = 0; m < 4; ++m)
#pragma unroll
          for (int n = 0; n < 4; ++n)
            acc[m][n] = __builtin_amdgcn_mfma_f32_16x16x32_bf16(af[m], bf[n], acc[m][n], 0, 0, 0);
      }
      __syncthreads();
    }
  }
  // RoPE epilogue: pairs (2j,2j+1) along co sit in adjacent lanes
  int par = lane & 1;
#pragma unroll
  for (int n = 0; n < 4; ++n) {
    int co = co0 + wc * 64 + n * 16 + l15;
    int j = (co & 127) >> 1;
    float th = exp2f(-(float)j * 0.20762050593f);  // 10000^(-j/64)
    float sth, cth;
    fsincos(th, &sth, &cth);
#pragma unroll
    for (int m = 0; m < 4; ++m) {
      int pxb = p0 + wr * 64 + m * 16 + hi4 * 4;
      float s0, c0;
      fsincos((float)pxb * th, &s0, &c0);
#pragma unroll
      for (int r = 0; r < 4; ++r) {
        float xv = acc[m][n][r];
        float ov = __shfl_xor(xv, 1);
        float y = par ? fmaf(ov, s0, xv * c0) : fmaf(xv, c0, -ov * s0);
        out[((size_t)b * 4096 + (pxb + r)) * Cout + co] = f2bf(y);
        float c1 = c0 * cth - s0 * sth;       // rotate angle by th (px+1)
        s0 = fmaf(c0, sth, s0 * cth);
        c0 = c1;
      }
    }
  }
}

// ================================================= 64^2 conv body (K,V), 32KB LDS
template <int TRANS_OUT, int ROPE>
__device__ __forceinline__ void conv64_body(
    const us* __restrict__ inT, const us* __restrict__ wp,
    us* __restrict__ out, int Cout, int logCoT, int bid, int ngrid, us* sh) {
  int nchunk = ngrid >> 3;
  int v = (bid & 7) * nchunk + (bid >> 3);
  int yt = v & 15;
  int cot = (v >> 4) & ((1 << logCoT) - 1);
  int b = v >> (4 + logCoT);
  int p0 = yt * 64, co0 = cot * 64;
  const int W = 32, logW = 5, padW = 34, HW = 1024;
  int tid = threadIdx.x;
  int wave = tid >> 6, lane = tid & 63, l15 = lane & 15, hi4 = lane >> 4;
  f32x4 acc[4];
#pragma unroll
  for (int i = 0; i < 4; ++i) acc[i] = (f32x4){0.f, 0.f, 0.f, 0.f};

  int arow[2], brow[2];
#pragma unroll
  for (int c = 0; c < 2; ++c) {
    int row = (wave * 2 + c) * 8 + (lane >> 3);
    int g = (lane & 7) ^ (row & 7);
    int px = p0 + row;
    int y = px >> logW, x = px & (W - 1);
    arow[c] = (y * padW + x) * 512 + g * 8;
    brow[c] = (co0 + row) * 512 + g * 8;
  }
  int rowA[4], rowB0 = (16 * wave + l15) * 64;
#pragma unroll
  for (int i = 0; i < 4; ++i) rowA[i] = (i * 16 + l15) * 64;

  const us* abase = inT + (size_t)b * padW * padW * 512;

  auto stage = [&](int buf, int t, int ci) {
    int ky = (t * 11) >> 5, kx = t - ky * 3;
    const us* as = abase + (ky * padW + kx) * 512 + ci;
    const us* bs = wp + (size_t)t * Cout * 512 + ci;
    us* la = sh + buf * 8192;
    us* lb = la + 4096;
#pragma unroll
    for (int c = 0; c < 2; ++c) {
      gload16(as + arow[c], la + (wave * 2 + c) * 512);
      gload16(bs + brow[c], lb + (wave * 2 + c) * 512);
    }
  };

  stage(0, 0, 0);
  __syncthreads();
  for (int cc = 0; cc < 8; ++cc) {
#pragma unroll
    for (int t = 0; t < 9; ++t) {
      int s = cc * 9 + t;
      int cur = s & 1;
      if (s < 71) {
        int tn = (t == 8) ? 0 : t + 1;
        int cn = (t == 8) ? (cc + 1) << 6 : cc << 6;
        stage(cur ^ 1, tn, cn);
      }
      const us* la = sh + cur * 8192;
      const us* lb = la + 4096;
#pragma unroll
      for (int ksi = 0; ksi < 2; ++ksi) {
        int ks = ksi ^ (wave & 1);                       // phase de-alignment
        int gb = ((ks * 4 + hi4) ^ (l15 & 7)) * 8;
        short8 bf = *(const short8*)(lb + rowB0 + gb);
#pragma unroll
        for (int i = 0; i < 4; ++i) {
          short8 af = *(const short8*)(la + rowA[i] + gb);
          acc[i] = __builtin_amdgcn_mfma_f32_16x16x32_bf16(af, bf, acc[i], 0, 0, 0);
        }
      }
      __syncthreads();
    }
  }
  if (ROPE) {
    int co = co0 + 16 * wave + l15;
    int j = (co & 127) >> 1;
    float th = exp2f(-(float)j * 0.20762050593f);
    float sth, cth;
    fsincos(th, &sth, &cth);
    int par = lane & 1;
#pragma unroll
    for (int i = 0; i < 4; ++i) {
      int pxb = p0 + i * 16 + hi4 * 4;
      float s0, c0;
      fsincos((float)pxb * th, &s0, &c0);
#pragma unroll
      for (int r = 0; r < 4; ++r) {
        float xv = acc[i][r];
        float ov = __shfl_xor(xv, 1);
        float y = par ? fmaf(ov, s0, xv * c0) : fmaf(xv, c0, -ov * s0);
        out[((size_t)b * HW + (pxb + r)) * Cout + co] = f2bf(y);
        float c1 = c0 * cth - s0 * sth;
        s0 = fmaf(c0, sth, s0 * cth);
        c0 = c1;
      }
    }
  } else {
#pragma unroll
    for (int i = 0; i < 4; ++i)
#pragma unroll
      for (int r = 0; r < 4; ++r) {
        int px = TRANS_OUT ? (p0 + (hi4 * 4 + r) * 4 + i)  // sigma(k)=(k%16)*4+k/16
                           : (p0 + i * 16 + hi4 * 4 + r);
        int co = co0 + 16 * wave + l15;
        us val = f2bf(acc[i][r]);
        if (TRANS_OUT)
          out[((size_t)b * Cout + co) * HW + px] = val;
        else
          out[((size_t)b * HW + px) * Cout + co] = val;
      }
  }
}

__global__ __launch_bounds__(256) void conv64_all(
    const us* __restrict__ cpadT, const us* __restrict__ wkp,
    const us* __restrict__ wvp, us* __restrict__ kb, us* __restrict__ vT) {
  __shared__ __align__(16) us sh[2][2][64][64];  // 32 KB
  int bid = blockIdx.x;
  if (bid < 256) conv64_body<0, 1>(cpadT, wkp, kb, 512, 3, bid, 256, &sh[0][0][0][0]);
  else           conv64_body<1, 0>(cpadT, wvp, vT, 256, 2, bid - 256, 128, &sh[0][0][0][0]);
}

// ================================================= final conv: 128co x 64px tile, grid 512
__global__ __launch_bounds__(256) void conv128_out(
    const us* __restrict__ apad, const us* __restrict__ wp,
    float* __restrict__ out) {
  __shared__ __align__(16) us lds[2][12288];   // [buf][A 128x64 | B 64x64]
  int bid = blockIdx.x;                        // 512 blocks
  int v = (bid & 7) * 64 + (bid >> 3);         // chunked XCD swizzle
  int pxt = v & 63, cot = (v >> 6) & 3, b = v >> 8;
  int p0 = pxt * 64, co0 = cot * 128;
  int tid = threadIdx.x;
  int wave = tid >> 6, lane = tid & 63, l15 = lane & 15, hi4 = lane >> 4;
  int wr = wave >> 1, wc = wave & 1;
  f32x4 acc[4][2];
#pragma unroll
  for (int m = 0; m < 4; ++m)
#pragma unroll
    for (int n = 0; n < 2; ++n) acc[m][n] = (f32x4){0.f, 0.f, 0.f, 0.f};

  int arow[4], brow[2];
#pragma unroll
  for (int c = 0; c < 4; ++c) {
    int row = c * 32 + (tid >> 3);
    int g = (tid & 7) ^ (row & 7);
    arow[c] = (co0 + row) * 512 + g * 8;       // weight rows (co)
  }
#pragma unroll
  for (int c = 0; c < 2; ++c) {
    int row = c * 32 + (tid >> 3);
    int g = (tid & 7) ^ (row & 7);
    int px = p0 + row;
    int y = px >> 6, x = px & 63;
    brow[c] = (y * 66 + x) * 512 + g * 8;      // pixel rows
  }
  int rowA[4], rowB[2];
#pragma unroll
  for (int m = 0; m < 4; ++m) rowA[m] = (wr * 64 + m * 16 + l15) * 64;
#pragma unroll
  for (int n = 0; n < 2; ++n) rowB[n] = (wc * 32 + n * 16 + l15) * 64;
  const us* bbase = apad + (size_t)b * 4356 * 512;

  auto stage = [&](int buf, int t, int ci) {
    int ky = (t * 11) >> 5, kx = t - ky * 3;
    const us* as = wp + (size_t)t * 512 * 512 + ci;
    const us* bs = bbase + (ky * 66 + kx) * 512 + ci;
    us* la = &lds[buf][0];
    us* lb = la + 8192;
#pragma unroll
    for (int c = 0; c < 4; ++c)
      gload16(as + arow[c], la + c * 2048 + wave * 512);
#pragma unroll
    for (int c = 0; c < 2; ++c)
      gload16(bs + brow[c], lb + c * 2048 + wave * 512);
  };

  stage(0, 0, 0);
  __syncthreads();
  for (int cc = 0; cc < 8; ++cc) {
#pragma unroll
    for (int t = 0; t < 9; ++t) {
      int s = cc * 9 + t;
      int cur = s & 1;
      if (s < 71) {
        int tn = (t == 8) ? 0 : t + 1;
        int cn = (t == 8) ? (cc + 1) << 6 : cc << 6;
        stage(cur ^ 1, tn, cn);
      }
      const us* la = &lds[cur][0];
      const us* lb = la + 8192;
#pragma unroll
      for (int ksi = 0; ksi < 2; ++ksi) {
        int ks = ksi ^ wc;                               // phase de-alignment
        int gb = ((ks * 4 + hi4) ^ (l15 & 7)) * 8;
        short8 af[4], bf[2];
#pragma unroll
        for (int m = 0; m < 4; ++m) af[m] = *(const short8*)(la + rowA[m] + gb);
#pragma unroll
        for (int n = 0; n < 2; ++n) bf[n] = *(const short8*)(lb + rowB[n] + gb);
#pragma unroll
        for (int m = 0; m < 4; ++m)
#pragma unroll
          for (int n = 0; n < 2; ++n)
            acc[m][n] = __builtin_amdgcn_mfma_f32_16x16x32_bf16(af[m], bf[n], acc[m][n], 0, 0, 0);
      }
      __syncthreads();
    }
  }
#pragma unroll
  for (int m = 0; m < 4; ++m)
#pragma unroll
    for (int n = 0; n < 2; ++n)
#pragma unroll
      for (int r = 0; r < 4; ++r) {
        int co = co0 + wr * 64 + m * 16 + hi4 * 4 + r;
        int px = p0 + wc * 32 + n * 16 + l15;
        out[((size_t)b * 512 + co) * 4096 + px] = acc[m][n][r];
      }
}

// ================================================= differential GQA attention + RMSNorm
// QBLK=64 (grid 1024); R7 sync structure (vmcnt(6), 2 barriers). Unchanged.
__global__ __launch_bounds__(256) void attn_kernel(
    const us* __restrict__ qb, const us* __restrict__ kb,
    const us* __restrict__ vT, const float* __restrict__ lam,
    us* __restrict__ apad) {
  int qt = blockIdx.x, h = blockIdx.y, b = blockIdx.z;
  int kvh = h >> 1;
  int tid = threadIdx.x;
  int wave = tid >> 6, lane = tid & 63, l15 = lane & 15, hi4 = lane >> 4;
  __shared__ __align__(16) us Klds[2][8192];   // [buf][64 k rows][128 d]
  __shared__ __align__(16) us Vlds[2][4096];   // [buf][64 dv rows][64 k']
  __shared__ __align__(16) us Plds[4][16][72];

  int q0 = qt * 64;
  short8 qf[2][2];  // [m][ks]
  {
    const us* qsrc =
        qb + ((size_t)(b * 4096 + q0 + wave * 16 + l15)) * 1024 + h * 128 + hi4 * 8;
#pragma unroll
    for (int m = 0; m < 2; ++m)
#pragma unroll
      for (int ks = 0; ks < 2; ++ks)
        qf[m][ks] = *(const short8*)(qsrc + m * 64 + ks * 32);
  }

  float sumd[2][4];
  f32x4 accO[2][4];
#pragma unroll
  for (int m = 0; m < 2; ++m)
#pragma unroll
    for (int r = 0; r < 4; ++r) {
      sumd[m][r] = 0.f;
      accO[m][r] = (f32x4){0.f, 0.f, 0.f, 0.f};
    }
  float lamh = lam[h];

  const us* kbase0 = kb + (size_t)b * 524288 + kvh * 128;
  const us* vbase0 = vT + ((size_t)(b * 256 + kvh * 64)) * 1024;
  int krow[4], vrow[2];
#pragma unroll
  for (int c = 0; c < 4; ++c) {
    int row = (wave * 4 + c) * 4 + hi4;
    int g = (l15 & 8) | ((l15 & 7) ^ (row & 7));
    krow[c] = row * 512 + g * 8;
  }
#pragma unroll
  for (int c = 0; c < 2; ++c) {
    int row = (wave * 2 + c) * 8 + (lane >> 3);
    int g = (lane & 7) ^ (row & 7);
    vrow[c] = row * 1024 + g * 8;
  }
  int kg0[2], kg1[2], vg[2];
#pragma unroll
  for (int m = 0; m < 2; ++m) {
    kg0[m] = (m * 8 | (hi4 ^ (l15 & 7))) * 8;
    kg1[m] = (m * 8 | ((4 + hi4) ^ (l15 & 7))) * 8;
  }
#pragma unroll
  for (int ks = 0; ks < 2; ++ks) vg[ks] = ((ks * 4 + hi4) ^ (l15 & 7)) * 8;

  auto stage = [&](int buf, int kt2) {
    const us* kk = kbase0 + (size_t)kt2 * 32768;
    const us* vv = vbase0 + kt2 * 64;
#pragma unroll
    for (int c = 0; c < 4; ++c)
      gload16(kk + krow[c], &Klds[buf][(wave * 4 + c) * 512]);
#pragma unroll
    for (int c = 0; c < 2; ++c)
      gload16(vv + vrow[c], &Vlds[buf][(wave * 2 + c) * 512]);
  };

  const float cexp = 0.18033688f;  // 0.125 * log2(e)
  stage(0, 0);
  for (int kt = 0; kt < 16; ++kt) {
    int cur = kt & 1;
    if (kt < 15) {
      stage(cur ^ 1, kt + 1);
      asm volatile("s_waitcnt vmcnt(6)" ::: "memory");
    } else {
      asm volatile("s_waitcnt vmcnt(0)" ::: "memory");
    }
    __builtin_amdgcn_s_barrier();
    __builtin_amdgcn_sched_barrier(0);

    short8 vf[2][4];
#pragma unroll
    for (int ks = 0; ks < 2; ++ks)
#pragma unroll
      for (int nf = 0; nf < 4; ++nf)
        vf[ks][nf] = *(const short8*)&Vlds[cur][(nf * 16 + l15) * 64 + vg[ks]];

#pragma unroll
    for (int m = 0; m < 2; ++m) {
      short8 kf[4][2];
#pragma unroll
      for (int nf = 0; nf < 4; ++nf) {
        kf[nf][0] = *(const short8*)&Klds[cur][(nf * 16 + l15) * 128 + kg0[m]];
        kf[nf][1] = *(const short8*)&Klds[cur][(nf * 16 + l15) * 128 + kg1[m]];
      }
      f32x4 s[4];
      __builtin_amdgcn_s_setprio(1);
#pragma unroll
      for (int nf = 0; nf < 4; ++nf) {
        f32x4 z = (f32x4){0.f, 0.f, 0.f, 0.f};
        z = __builtin_amdgcn_mfma_f32_16x16x32_bf16(qf[m][0], kf[nf][0], z, 0, 0, 0);
        z = __builtin_amdgcn_mfma_f32_16x16x32_bf16(qf[m][1], kf[nf][1], z, 0, 0, 0);
        s[nf] = z;
      }
      __builtin_amdgcn_s_setprio(0);
#pragma unroll
      for (int r = 0; r < 4; ++r) {
        float p0 = fast_exp2(s[0][r] * cexp);
        float p1 = fast_exp2(s[1][r] * cexp);
        float p2 = fast_exp2(s[2][r] * cexp);
        float p3 = fast_exp2(s[3][r] * cexp);
        sumd[m][r] += (p0 + p1) + (p2 + p3);
        unsigned int w0 = cvt_pk_bf16(p0, p1);
        unsigned int w1 = cvt_pk_bf16(p2, p3);
        *(uint2*)&Plds[wave][hi4 * 4 + r][l15 * 4] = make_uint2(w0, w1);
      }
      __builtin_amdgcn_s_setprio(1);
#pragma unroll
      for (int ks = 0; ks < 2; ++ks) {
        short8 pf = *(const short8*)&Plds[wave][l15][ks * 32 + hi4 * 8];
#pragma unroll
        for (int nf = 0; nf < 4; ++nf)
          accO[m][nf] =
              __builtin_amdgcn_mfma_f32_16x16x32_bf16(pf, vf[ks][nf], accO[m][nf], 0, 0, 0);
      }
      __builtin_amdgcn_s_setprio(0);
    }
    asm volatile("s_waitcnt lgkmcnt(0)" ::: "memory");
    __builtin_amdgcn_s_barrier();
    __builtin_amdgcn_sched_barrier(0);
  }

  // epilogue: denom reduce, combine mults, RMSNorm, scale 0.8
#pragma unroll
  for (int m = 0; m < 2; ++m)
#pragma unroll
    for (int r = 0; r < 4; ++r) {
      float sx = sumd[m][r];
      sx += __shfl_xor(sx, 1);
      sx += __shfl_xor(sx, 2);
      sx += __shfl_xor(sx, 4);
      sx += __shfl_xor(sx, 8);
      sumd[m][r] = sx;
    }
#pragma unroll
  for (int r = 0; r < 4; ++r) {
    float inv0 = 1.f / sumd[0][r];
    float inv1 = lamh / sumd[1][r];
    float comb[4];
    float ss = 0.f;
#pragma unroll
    for (int nf = 0; nf < 4; ++nf) {
      comb[nf] = accO[0][nf][r] * inv0 + accO[1][nf][r] * inv1;
      ss += comb[nf] * comb[nf];
    }
    ss += __shfl_xor(ss, 1);
    ss += __shfl_xor(ss, 2);
    ss += __shfl_xor(ss, 4);
    ss += __shfl_xor(ss, 8);
    float sc = rsqrtf(ss * (1.f / 64.f) + 1e-8f) * 0.8f;
    int q = q0 + wave * 16 + hi4 * 4 + r;
    int y = q >> 6, x = q & 63;
    size_t oaddr = ((size_t)b * 4356 + (size_t)(y + 1) * 66 + (x + 1)) * 512 + h * 64;
#pragma unroll
    for (int nf = 0; nf < 4; ++nf) apad[oaddr + nf * 16 + l15] = f2bf(comb[nf] * sc);
  }
}

// ============================================================== launch
extern "C" void kernel_launch(void* const* d_in, const int* in_sizes, int n_in,
                              void* d_out, int out_size, void* d_ws, size_t ws_size,
                              hipStream_t stream) {
  const float* x     = (const float*)d_in[0];
  const float* cross = (const float*)d_in[1];
  const float* wq    = (const float*)d_in[2];
  const float* wk    = (const float*)d_in[3];
  const float* wv    = (const float*)d_in[4];
  const float* wo    = (const float*)d_in[5];
  const float* lq1   = (const float*)d_in[6];
  const float* lq2   = (const float*)d_in[7];
  const float* lk1   = (const float*)d_in[8];
  const float* lk2   = (const float*)d_in[9];
  float* out = (float*)d_out;

  char* ws = (char*)d_ws;
  size_t off = 0;
  auto nxt = [&](size_t bytes) { char* p = ws + off; off += bytes; return p; };
  us* xpadT = (us*)nxt(8921088);   // [2][4356][512] bf16
  us* cpadT = (us*)nxt(2367488);   // [2][1156][512] bf16
  us* apad  = (us*)nxt(8921088);   // [2][4356][512] bf16
  us* wqp = (us*)nxt(9437184);     // [9][1024][512]
  us* wkp = (us*)nxt(4718592);     // [9][512][512]
  us* wvp = (us*)nxt(2359296);     // [9][256][512]
  us* wop = (us*)nxt(4718592);     // [9][512][512]
  us* qb  = (us*)nxt(16777216);    // [2][4096][1024] (rope'd)
  us* kb  = (us*)nxt(2097152);     // [2][1024][512]  (rope'd)
  us* vT  = (us*)nxt(1048576);     // [2][256][1024] (sigma-permuted along k)
  float* lam = (float*)nxt(256);   // [8]
  (void)ws_size; (void)in_sizes; (void)n_in; (void)out_size;

  prep_all<<<4167, 256, 0, stream>>>(x, cross, wq, wk, wv, wo,
                                     lq1, lq2, lk1, lk2,
                                     xpadT, cpadT, apad, wqp, wkp, wvp, wop, lam);
  conv128_fwd<<<512, 256, 0, stream>>>(xpadT, wqp, qb, 1024);
  conv64_all<<<384, 256, 0, stream>>>(cpadT, wkp, wvp, kb, vT);
  attn_kernel<<<dim3(64, 8, 2), 256, 0, stream>>>(qb, kb, vT, lam, apad);
  conv128_out<<<512, 256, 0, stream>>>(apad, wop, out);
}